// Round 4
// baseline (792.241 us; speedup 1.0000x reference)
//
#include <hip/hip_runtime.h>

// ---------------- problem constants ----------------
#define B_    64
#define TOK_  576
#define DIM_  1024
#define TXT_  512
#define NT_   1000
#define NTQ_  1024                 // kvn padded rows (zero-filled 1000..1023)
#define NTP_  1024                 // kvt padded cols / P padded cols
#define H_    24
#define BT_   (B_ * TOK_)          // 36864 rows
static constexpr float SCALE_ = 0.0441941738241592f;   // 512^-0.5

typedef __bf16 bf16x8 __attribute__((ext_vector_type(8)));
typedef float  f32x4  __attribute__((ext_vector_type(4)));

__device__ __forceinline__ unsigned short f2bf(float f) {
    unsigned u = __float_as_uint(f);
    u += 0x7fffu + ((u >> 16) & 1u);
    return (unsigned short)(u >> 16);
}
__device__ __forceinline__ float bf2f(unsigned short h) {
    return __uint_as_float(((unsigned)h) << 16);
}
__device__ __forceinline__ f32x4 mfma16(bf16x8 a, bf16x8 b, f32x4 c) {
    return __builtin_amdgcn_mfma_f32_16x16x32_bf16(a, b, c, 0, 0, 0);
}
__device__ __forceinline__ void unpack8(uint4 v, float* f) {
    unsigned a0 = v.x, a1 = v.y, a2 = v.z, a3 = v.w;
    f[0] = bf2f((unsigned short)(a0 & 0xffff)); f[1] = bf2f((unsigned short)(a0 >> 16));
    f[2] = bf2f((unsigned short)(a1 & 0xffff)); f[3] = bf2f((unsigned short)(a1 >> 16));
    f[4] = bf2f((unsigned short)(a2 & 0xffff)); f[5] = bf2f((unsigned short)(a2 >> 16));
    f[6] = bf2f((unsigned short)(a3 & 0xffff)); f[7] = bf2f((unsigned short)(a3 >> 16));
}
// order-preserving float->uint encoding for atomicMax over signed floats
__device__ __forceinline__ unsigned encmax(float f) {
    unsigned u = __float_as_uint(f);
    return (u & 0x80000000u) ? ~u : (u | 0x80000000u);
}
__device__ __forceinline__ float decmax(unsigned k) {
    unsigned u = (k & 0x80000000u) ? (k ^ 0x80000000u) : ~k;
    return __uint_as_float(u);
}

// async global->LDS, 16B per lane; lds base wave-uniform, lanes land at base + lane*16
typedef const __attribute__((address_space(1))) unsigned int* as1_u32p;
typedef __attribute__((address_space(3))) unsigned int* as3_u32p;
__device__ __forceinline__ void gll16(const void* g, void* l) {
    __builtin_amdgcn_global_load_lds((as1_u32p)g, (as3_u32p)l, 16, 0, 0);
}

// ---------------- weight prep ----------------
// Wq (1024x512 f32), rows pre-scaled by LN gamma -> WqT bf16 [branch][512][1024]
__global__ void k_prep_wq(const float* __restrict__ wq1, const float* __restrict__ wq2,
                          const float* __restrict__ g1, const float* __restrict__ g2,
                          unsigned short* __restrict__ wqt) {
    __shared__ float tile[64][68];
    int bx = blockIdx.x, t = threadIdx.x;
    int br = bx >> 7, kt = (bx >> 3) & 15, nt = bx & 7;
    const float* wq = br ? wq2 : wq1;
    const float* gg = br ? g2 : g1;
#pragma unroll
    for (int i = 0; i < 4; ++i) {
        int idx4 = t + i * 256;
        int kl = idx4 >> 4, n4 = (idx4 & 15) * 4;
        float gv = gg[kt * 64 + kl];
        float4 v = *reinterpret_cast<const float4*>(wq + (size_t)(kt * 64 + kl) * 512 + nt * 64 + n4);
        tile[kl][n4 + 0] = v.x * gv; tile[kl][n4 + 1] = v.y * gv;
        tile[kl][n4 + 2] = v.z * gv; tile[kl][n4 + 3] = v.w * gv;
    }
    __syncthreads();
#pragma unroll
    for (int i = 0; i < 4; ++i) {
        int idx4 = t + i * 256;
        int nl = idx4 >> 4, k4 = (idx4 & 15) * 4;
        ushort4 o = make_ushort4(f2bf(tile[k4 + 0][nl]), f2bf(tile[k4 + 1][nl]),
                                 f2bf(tile[k4 + 2][nl]), f2bf(tile[k4 + 3][nl]));
        *reinterpret_cast<ushort4*>(wqt + (size_t)br * 512 * 1024 + (size_t)(nt * 64 + nl) * 1024 + kt * 64 + k4) = o;
    }
}

// qbias[br][e] = sum_d beta[d] * Wq[d][e]
__global__ void k_qbias(const float* __restrict__ wq1, const float* __restrict__ wq2,
                        const float* __restrict__ b1, const float* __restrict__ b2,
                        float* __restrict__ qbias) {
    int br = blockIdx.x >> 3, e0 = (blockIdx.x & 7) * 64;
    int t = threadIdx.x;
    int e = e0 + (t & 63), part = t >> 6;
    const float* wq = br ? wq2 : wq1;
    const float* bb = br ? b2 : b1;
    float s = 0.f;
    for (int d = part * 256; d < part * 256 + 256; ++d) s += bb[d] * wq[(size_t)d * 512 + e];
    __shared__ float red[256];
    red[t] = s;
    __syncthreads();
    if (t < 64) qbias[br * 512 + e0 + t] = red[t] + red[64 + t] + red[128 + t] + red[192 + t];
}

__global__ void k_f2bf(const float* __restrict__ src, unsigned short* __restrict__ dst, int n4) {
    int i = blockIdx.x * blockDim.x + threadIdx.x;
    if (i < n4) {
        float4 v = *reinterpret_cast<const float4*>(src + (size_t)i * 4);
        ushort4 o = make_ushort4(f2bf(v.x), f2bf(v.y), f2bf(v.z), f2bf(v.w));
        *reinterpret_cast<ushort4*>(dst + (size_t)i * 4) = o;
    }
}

// ---------------- fused kv layernorm + transpose ----------------
// block: (b, 32-row n-group). Writes kvn [b][n_pad][e] and kvt [b][e][n_pad].
__global__ __launch_bounds__(256, 4) void k_kvlnt(const float* __restrict__ tf,
                                                  const float* __restrict__ g,
                                                  const float* __restrict__ bta,
                                                  unsigned short* __restrict__ kvn,
                                                  unsigned short* __restrict__ kvt) {
    __shared__ unsigned short tile[32][514];      // +2 pad: uint-aligned, conflict-free reads
    __shared__ float red[32][8][2];
    __shared__ float stat[32][2];
    int b = blockIdx.x >> 5, n0 = (blockIdx.x & 31) * 32;
    int t = threadIdx.x, r = t >> 3, p = t & 7;   // row 0..31, part 0..7 (64 elems each)
    int n = n0 + r;
    bool valid = n < NT_;
    const float* src = tf + ((size_t)n * B_ + b) * TXT_ + p * 64;
    float s = 0.f, ss = 0.f;
    if (valid) {
#pragma unroll
        for (int j = 0; j < 16; ++j) {
            float4 v = *reinterpret_cast<const float4*>(src + j * 4);
            s += v.x + v.y + v.z + v.w;
            ss += v.x * v.x + v.y * v.y + v.z * v.z + v.w * v.w;
        }
    }
    red[r][p][0] = s; red[r][p][1] = ss;
    __syncthreads();
    if (p == 0) {
        float S = 0.f, SS = 0.f;
#pragma unroll
        for (int k = 0; k < 8; ++k) { S += red[r][k][0]; SS += red[r][k][1]; }
        float m = S * (1.f / TXT_);
        stat[r][0] = m;
        stat[r][1] = rsqrtf(SS * (1.f / TXT_) - m * m + 1e-5f);
    }
    __syncthreads();
    float m = stat[r][0], rs = stat[r][1];
    unsigned short* dstn = kvn + ((size_t)b * NTQ_ + n) * TXT_ + p * 64;
#pragma unroll
    for (int j = 0; j < 16; ++j) {
        int e = p * 64 + j * 4;
        unsigned short h0 = 0, h1 = 0, h2 = 0, h3 = 0;
        if (valid) {
            float4 v = *reinterpret_cast<const float4*>(src + j * 4);
            float4 gv = *reinterpret_cast<const float4*>(g + e);
            float4 bv = *reinterpret_cast<const float4*>(bta + e);
            h0 = f2bf((v.x - m) * rs * gv.x + bv.x);
            h1 = f2bf((v.y - m) * rs * gv.y + bv.y);
            h2 = f2bf((v.z - m) * rs * gv.z + bv.z);
            h3 = f2bf((v.w - m) * rs * gv.w + bv.w);
        }
        *reinterpret_cast<ushort4*>(dstn + j * 4) = make_ushort4(h0, h1, h2, h3);
        unsigned* tw = reinterpret_cast<unsigned*>(&tile[r][e]);   // 4B aligned (e%4==0, stride even)
        tw[0] = (unsigned)h0 | ((unsigned)h1 << 16);
        tw[1] = (unsigned)h2 | ((unsigned)h3 << 16);
    }
    __syncthreads();
    // transpose out: each thread 2 e-rows x 32 n
#pragma unroll
    for (int ee = 0; ee < 2; ++ee) {
        int e = ee * 256 + t;
        unsigned short* dstt = kvt + ((size_t)b * TXT_ + e) * NTP_ + n0;
#pragma unroll
        for (int j4 = 0; j4 < 8; ++j4) {
            ushort4 o = make_ushort4(tile[j4 * 4 + 0][e], tile[j4 * 4 + 1][e],
                                     tile[j4 * 4 + 2][e], tile[j4 * 4 + 3][e]);
            *reinterpret_cast<ushort4*>(dstt + j4 * 4) = o;
        }
    }
}

// ---------------- x layernorm (normalized only; gamma/beta folded into Wq) ----------------
__global__ void k_xln(const float* __restrict__ x, unsigned short* __restrict__ xn) {
    int bt = blockIdx.x;                   // b*TOK + t
    int b = bt / TOK_, tk = bt - b * TOK_;
    const float* src = x + ((size_t)(tk + 1) * B_ + b) * DIM_;
    int t = threadIdx.x;                   // 256 threads, 4 floats each
    float4 v = *reinterpret_cast<const float4*>(src + t * 4);
    float s = v.x + v.y + v.z + v.w;
    float ss = v.x * v.x + v.y * v.y + v.z * v.z + v.w * v.w;
#pragma unroll
    for (int d = 1; d < 64; d <<= 1) { s += __shfl_xor(s, d); ss += __shfl_xor(ss, d); }
    __shared__ float red[8];
    if ((t & 63) == 0) { red[t >> 6] = s; red[4 + (t >> 6)] = ss; }
    __syncthreads();
    s = red[0] + red[1] + red[2] + red[3];
    ss = red[4] + red[5] + red[6] + red[7];
    float m = s * (1.f / DIM_);
    float rs = rsqrtf(ss * (1.f / DIM_) - m * m + 1e-5f);
    int d0 = t * 4;
    ushort4 o = make_ushort4(f2bf((v.x - m) * rs), f2bf((v.y - m) * rs),
                             f2bf((v.z - m) * rs), f2bf((v.w - m) * rs));
    *reinterpret_cast<ushort4*>(xn + (size_t)bt * DIM_ + d0) = o;
}

// ---------------- 128x128xK bf16 GEMM mainloop, global_load_lds staging (m97 structure) ----------------
// A:[M][K], B:[N][K], both k-contiguous.
__device__ __forceinline__ void gemm_loop_gll(const unsigned short* __restrict__ A,
                                              const unsigned short* __restrict__ Bp,
                                              int K, unsigned short* a_lds, unsigned short* b_lds,
                                              int tid, f32x4 acc[4][4]) {
    const int l = tid & 63, w = tid >> 6;
    const int l16 = l & 15, lg = l >> 4;
    const int wm = w & 1, wn = w >> 1;
    const f32x4 fz = {0.f, 0.f, 0.f, 0.f};
#pragma unroll
    for (int mt = 0; mt < 4; ++mt)
#pragma unroll
        for (int nt = 0; nt < 4; ++nt) acc[mt][nt] = fz;
    const int lrow = l >> 3;               // 0..7
    const int k8g = (l & 7) ^ lrow;        // pre-swizzled source granule
    const int nk = K >> 6;
    for (int kt = 0; kt < nk; ++kt) {
#pragma unroll
        for (int i = 0; i < 4; ++i) {
            int row = i * 32 + w * 8 + lrow;
            gll16(A + (size_t)row * K + kt * 64 + k8g * 8, &a_lds[(i * 256 + w * 64) * 8]);
        }
#pragma unroll
        for (int i = 0; i < 4; ++i) {
            int row = i * 32 + w * 8 + lrow;
            gll16(Bp + (size_t)row * K + kt * 64 + k8g * 8, &b_lds[(i * 256 + w * 64) * 8]);
        }
        __syncthreads();
#pragma unroll
        for (int kk = 0; kk < 2; ++kk) {
            bf16x8 af[4], bff[4];
#pragma unroll
            for (int mt = 0; mt < 4; ++mt) {
                int row = wm * 64 + mt * 16 + l16;
                int gs = (kk * 4 + lg) ^ (row & 7);
                af[mt] = *reinterpret_cast<const bf16x8*>(a_lds + row * 64 + gs * 8);
            }
#pragma unroll
            for (int nt = 0; nt < 4; ++nt) {
                int row = wn * 64 + nt * 16 + l16;
                int gs = (kk * 4 + lg) ^ (row & 7);
                bff[nt] = *reinterpret_cast<const bf16x8*>(b_lds + row * 64 + gs * 8);
            }
#pragma unroll
            for (int mt = 0; mt < 4; ++mt)
#pragma unroll
                for (int nt = 0; nt < 4; ++nt)
                    acc[mt][nt] = mfma16(af[mt], bff[nt], acc[mt][nt]);
        }
        __syncthreads();
    }
}

// ---------------- 96x128xK variant (M-tile 96 keeps tiles inside one b: 576 = 6*96) ----------------
__device__ __forceinline__ void gemm_loop96(const unsigned short* __restrict__ A,
                                            const unsigned short* __restrict__ Bp,
                                            int K, unsigned short* a_lds, unsigned short* b_lds,
                                            int tid, f32x4 acc[3][4]) {
    const int l = tid & 63, w = tid >> 6;
    const int l16 = l & 15, lg = l >> 4;
    const int wm = w & 1, wn = w >> 1;
    const f32x4 fz = {0.f, 0.f, 0.f, 0.f};
#pragma unroll
    for (int mt = 0; mt < 3; ++mt)
#pragma unroll
        for (int nt = 0; nt < 4; ++nt) acc[mt][nt] = fz;
    const int lrow = l >> 3;
    const int k8g = (l & 7) ^ lrow;
    const int nk = K >> 6;
    for (int kt = 0; kt < nk; ++kt) {
#pragma unroll
        for (int i = 0; i < 3; ++i) {
            int row = i * 32 + w * 8 + lrow;
            gll16(A + (size_t)row * K + kt * 64 + k8g * 8, &a_lds[(i * 256 + w * 64) * 8]);
        }
#pragma unroll
        for (int i = 0; i < 4; ++i) {
            int row = i * 32 + w * 8 + lrow;
            gll16(Bp + (size_t)row * K + kt * 64 + k8g * 8, &b_lds[(i * 256 + w * 64) * 8]);
        }
        __syncthreads();
#pragma unroll
        for (int kk = 0; kk < 2; ++kk) {
            bf16x8 af[3], bff[4];
#pragma unroll
            for (int mt = 0; mt < 3; ++mt) {
                int row = wm * 48 + mt * 16 + l16;
                int gs = (kk * 4 + lg) ^ (row & 7);
                af[mt] = *reinterpret_cast<const bf16x8*>(a_lds + row * 64 + gs * 8);
            }
#pragma unroll
            for (int nt = 0; nt < 4; ++nt) {
                int row = wn * 64 + nt * 16 + l16;
                int gs = (kk * 4 + lg) ^ (row & 7);
                bff[nt] = *reinterpret_cast<const bf16x8*>(b_lds + row * 64 + gs * 8);
            }
#pragma unroll
            for (int mt = 0; mt < 3; ++mt)
#pragma unroll
                for (int nt = 0; nt < 4; ++nt)
                    acc[mt][nt] = mfma16(af[mt], bff[nt], acc[mt][nt]);
        }
        __syncthreads();
    }
}

// q GEMM:  q[br] = (xn @ (diag(g)Wq[br])^T + bias) * SCALE  -> bf16 (36864x512)
__global__ __launch_bounds__(256, 4) void k_qgemm(const unsigned short* __restrict__ xn,
                                                  const unsigned short* __restrict__ wqt,
                                                  const float* __restrict__ qbias,
                                                  unsigned short* __restrict__ qb) {
    int bid = blockIdx.x;                        // 2304 = 4bn x 288bm x 2br
    int vb = (bid & 7) * 288 + (bid >> 3);       // XCD-contiguous
    int bn = vb & 3;
    int t = vb >> 2;
    int br = (t >= 288) ? 1 : 0;
    int bm = t - br * 288;
    const unsigned short* A = xn + (size_t)bm * 128 * DIM_;
    const unsigned short* Bp = wqt + (size_t)br * 512 * 1024 + (size_t)bn * 128 * 1024;
    unsigned short* C = qb + (size_t)br * BT_ * TXT_;
    const float* bias = qbias + br * 512;
    __shared__ unsigned short a_lds[128 * 64];
    __shared__ unsigned short b_lds[128 * 64];
    f32x4 acc[4][4];
    gemm_loop_gll(A, Bp, DIM_, a_lds, b_lds, threadIdx.x, acc);
    const int l = threadIdx.x & 63, w = threadIdx.x >> 6;
    const int l16 = l & 15, lg = l >> 4, wm = w & 1, wn = w >> 1;
#pragma unroll
    for (int mt = 0; mt < 4; ++mt)
#pragma unroll
        for (int nt = 0; nt < 4; ++nt) {
            int col = bn * 128 + wn * 64 + nt * 16 + l16;
            float bv = bias[col];
#pragma unroll
            for (int r = 0; r < 4; ++r) {
                int row = bm * 128 + wm * 64 + mt * 16 + lg * 4 + r;
                C[(size_t)row * TXT_ + col] = f2bf((acc[mt][nt][r] + bv) * SCALE_);
            }
        }
}

// score GEMM: P = exp(q @ kvn^T) per branch, + row-sum atomics into denom
__global__ __launch_bounds__(256, 4) void k_score(const unsigned short* __restrict__ qbuf,
                                                  const unsigned short* __restrict__ kvn,
                                                  unsigned short* __restrict__ P,
                                                  float* __restrict__ denom, int br) {
    int bid = blockIdx.x;                        // 3072 = 64b x 6mt x 8nt
    int vb = (bid & 7) * 384 + (bid >> 3);       // XCD-contiguous, 8 b's per XCD
    int tile = vb % 48, b = vb / 48;
    int mt = tile >> 3, nt = tile & 7;
    const unsigned short* A = qbuf + ((size_t)br * BT_ + (size_t)b * TOK_ + mt * 96) * TXT_;
    const unsigned short* Bp = kvn + (size_t)b * NTQ_ * TXT_ + (size_t)nt * 128 * TXT_;
    __shared__ unsigned short a_lds[96 * 64];
    __shared__ unsigned short b_lds[128 * 64];
    f32x4 acc[3][4];
    gemm_loop96(A, Bp, TXT_, a_lds, b_lds, threadIdx.x, acc);
    const int l = threadIdx.x & 63, w = threadIdx.x >> 6;
    const int l16 = l & 15, lg = l >> 4, wm = w & 1, wn = w >> 1;
    float* dn = denom + (size_t)br * BT_;
#pragma unroll
    for (int mt2 = 0; mt2 < 3; ++mt2)
#pragma unroll
        for (int r = 0; r < 4; ++r) {
            int row = b * TOK_ + mt * 96 + wm * 48 + mt2 * 16 + lg * 4 + r;
            float s = 0.f;
#pragma unroll
            for (int nt2 = 0; nt2 < 4; ++nt2) {
                int col = nt * 128 + wn * 64 + nt2 * 16 + l16;
                float p = (col < NT_) ? __expf(acc[mt2][nt2][r]) : 0.f;
                s += p;
                P[(size_t)row * NTP_ + col] = f2bf(p);
            }
#pragma unroll
            for (int d = 1; d < 16; d <<= 1) s += __shfl_xor(s, d);
            if (l16 == 0) atomicAdd(&dn[row], s);
        }
}

// PV GEMM: O = (P @ kvt^T) / denom -> bf16; fused per-row sum (br0) / max (br1) atomics
__global__ __launch_bounds__(256, 4) void k_pv(const unsigned short* __restrict__ P,
                                               const unsigned short* __restrict__ kvt,
                                               const float* __restrict__ denom,
                                               unsigned short* __restrict__ ob,
                                               float* __restrict__ avgs,
                                               unsigned* __restrict__ maxe, int br) {
    int bid = blockIdx.x;                        // 1536 = 64b x 6mt x 4nt
    int vb = (bid & 7) * 192 + (bid >> 3);       // XCD-contiguous, 8 b's per XCD
    int tile = vb % 24, b = vb / 24;
    int mt = tile >> 2, nt = tile & 3;
    const unsigned short* A = P + ((size_t)b * TOK_ + mt * 96) * NTP_;
    const unsigned short* Bp = kvt + (size_t)b * TXT_ * NTP_ + (size_t)nt * 128 * NTP_;
    __shared__ unsigned short a_lds[96 * 64];
    __shared__ unsigned short b_lds[128 * 64];
    f32x4 acc[3][4];
    gemm_loop96(A, Bp, NTP_, a_lds, b_lds, threadIdx.x, acc);
    const int l = threadIdx.x & 63, w = threadIdx.x >> 6;
    const int l16 = l & 15, lg = l >> 4, wm = w & 1, wn = w >> 1;
    const float* dn = denom + (size_t)br * BT_;
#pragma unroll
    for (int mt2 = 0; mt2 < 3; ++mt2)
#pragma unroll
        for (int r = 0; r < 4; ++r) {
            int row = b * TOK_ + mt * 96 + wm * 48 + mt2 * 16 + lg * 4 + r;
            float inv = 1.f / dn[row];
            unsigned short* dst = ob + ((size_t)br * BT_ + row) * TXT_;
            float sum = 0.f, mx = -1e30f;
#pragma unroll
            for (int nt2 = 0; nt2 < 4; ++nt2) {
                int col = nt * 128 + wn * 64 + nt2 * 16 + l16;
                float o = acc[mt2][nt2][r] * inv;
                dst[col] = f2bf(o);
                sum += o;
                mx = fmaxf(mx, o);
            }
#pragma unroll
            for (int d = 1; d < 16; d <<= 1) {
                sum += __shfl_xor(sum, d);
                mx = fmaxf(mx, __shfl_xor(mx, d));
            }
            if (l16 == 0) {
                if (br == 0) atomicAdd(&avgs[row], sum);
                else         atomicMax(&maxe[row], encmax(mx));
            }
        }
}

// final GEMM: y = xse (36864x512) @ Wf^T (1024x512) -> fp32 scattered into out layout
__global__ __launch_bounds__(256, 4) void k_fgemm(const unsigned short* __restrict__ xse,
                                                  const unsigned short* __restrict__ wfb,
                                                  float* __restrict__ out) {
    int bid = blockIdx.x;                        // 2304 = 8bn x 288bm
    int vb = (bid & 7) * 288 + (bid >> 3);
    int bn = vb & 7, bm = vb >> 3;
    const unsigned short* A = xse + (size_t)bm * 128 * TXT_;
    const unsigned short* Bp = wfb + (size_t)bn * 128 * TXT_;
    __shared__ unsigned short a_lds[128 * 64];
    __shared__ unsigned short b_lds[128 * 64];
    f32x4 acc[4][4];
    gemm_loop_gll(A, Bp, TXT_, a_lds, b_lds, threadIdx.x, acc);
    const int l = threadIdx.x & 63, w = threadIdx.x >> 6;
    const int l16 = l & 15, lg = l >> 4, wm = w & 1, wn = w >> 1;
#pragma unroll
    for (int mt = 0; mt < 4; ++mt)
#pragma unroll
        for (int r = 0; r < 4; ++r) {
            int rowg = bm * 128 + wm * 64 + mt * 16 + lg * 4 + r;
            int b = rowg / TOK_, tk = rowg - b * TOK_;
            float* dst = out + ((size_t)(tk + 1) * B_ + b) * DIM_;
#pragma unroll
            for (int nt = 0; nt < 4; ++nt) {
                int col = bn * 128 + wn * 64 + nt * 16 + l16;
                dst[col] = acc[mt][nt][r];
            }
        }
}

// ---------------- x_se = o1*g1 + o2*g2 -> bf16, with gate conv fused (lane 0 per row) ----------------
__global__ void k_xse(const unsigned short* __restrict__ o1, const unsigned short* __restrict__ o2,
                      const float* __restrict__ avgs, const unsigned* __restrict__ maxe,
                      const float* __restrict__ cdw, unsigned short* __restrict__ xse) {
    int idx8 = blockIdx.x * 256 + threadIdx.x;    // < 36864*64
    int bt = idx8 >> 6, e8 = threadIdx.x & 63;
    float gg1 = 0.f, gg2 = 0.f;
    if (e8 == 0) {
        int b = bt / TOK_, hw = bt - b * TOK_, h = hw / H_, ww = hw - h * H_;
        float a1 = 0.f, a2 = 0.f;
#pragma unroll
        for (int ky = 0; ky < 3; ++ky)
#pragma unroll
            for (int kx = 0; kx < 3; ++kx) {
                int hh = h + ky - 1, wx = ww + kx - 1;
                if (hh >= 0 && hh < H_ && wx >= 0 && wx < H_) {
                    float wv = cdw[ky * 3 + kx];
                    int s = b * TOK_ + hh * H_ + wx;
                    a1 += wv * avgs[s] * (1.f / TXT_);
                    a2 += wv * decmax(maxe[s]);
                }
            }
        gg1 = 1.f / (1.f + __expf(-a1));
        gg2 = 1.f / (1.f + __expf(-a2));
    }
    gg1 = __shfl(gg1, 0);
    gg2 = __shfl(gg2, 0);
    float f1[8], f2[8];
    unpack8(*reinterpret_cast<const uint4*>(o1 + (size_t)bt * TXT_ + e8 * 8), f1);
    unpack8(*reinterpret_cast<const uint4*>(o2 + (size_t)bt * TXT_ + e8 * 8), f2);
    unsigned r[4];
#pragma unroll
    for (int j = 0; j < 4; ++j) {
        unsigned lo = f2bf(f1[2 * j] * gg1 + f2[2 * j] * gg2);
        unsigned hi = f2bf(f1[2 * j + 1] * gg1 + f2[2 * j + 1] * gg2);
        r[j] = lo | (hi << 16);
    }
    uint4 o = make_uint4(r[0], r[1], r[2], r[3]);
    *reinterpret_cast<uint4*>(xse + (size_t)bt * TXT_ + e8 * 8) = o;
}

// ---------------- launcher ----------------
extern "C" void kernel_launch(void* const* d_in, const int* in_sizes, int n_in,
                              void* d_out, int out_size, void* d_ws, size_t ws_size,
                              hipStream_t stream) {
    (void)in_sizes; (void)n_in; (void)out_size; (void)ws_size;
    const float* x    = (const float*)d_in[0];
    const float* tf   = (const float*)d_in[1];
    const float* lq1g = (const float*)d_in[2];
    const float* lq1b = (const float*)d_in[3];
    const float* lq2g = (const float*)d_in[4];
    const float* lq2b = (const float*)d_in[5];
    const float* lkvg = (const float*)d_in[6];
    const float* lkvb = (const float*)d_in[7];
    const float* wq1  = (const float*)d_in[8];
    const float* wq2  = (const float*)d_in[9];
    const float* cdw  = (const float*)d_in[10];
    const float* wf   = (const float*)d_in[11];
    float* out = (float*)d_out;

    char* ws = (char*)d_ws;
    size_t off = 0;
    auto carve = [&](size_t bytes) { char* p = ws + off; off += (bytes + 255) & ~(size_t)255; return p; };
    unsigned short* kvn  = (unsigned short*)carve((size_t)B_ * NTQ_ * TXT_ * 2);       // 67.1 MB
    unsigned short* kvt  = (unsigned short*)carve((size_t)B_ * TXT_ * NTP_ * 2);       // 67.1 MB
    unsigned short* wqt  = (unsigned short*)carve((size_t)2 * 512 * 1024 * 2);         // 2 MB
    unsigned short* wfb  = (unsigned short*)carve((size_t)1024 * 512 * 2);             // 1 MB
    float* qbias = (float*)carve((size_t)2 * 512 * 4);
    float* denom = (float*)carve((size_t)2 * BT_ * 4);                                 // 0.3 MB
    float* avgs  = (float*)carve((size_t)BT_ * 4);
    unsigned* maxe = (unsigned*)carve((size_t)BT_ * 4);
    unsigned short* xn   = (unsigned short*)carve((size_t)BT_ * DIM_ * 2);             // 75.5 MB
    unsigned short* qbuf = (unsigned short*)carve((size_t)2 * BT_ * TXT_ * 2);         // 75.5 MB
    unsigned short* ob   = (unsigned short*)carve((size_t)2 * BT_ * TXT_ * 2);         // 75.5 MB
    unsigned short* Pm   = xn;     // P (36864x1024 bf16, per branch): xn dead after k_qgemm
    unsigned short* xse  = qbuf;   // safe: qbuf dead after last k_score

    // row 0 of output = x_cls
    hipMemcpyAsync(out, x, (size_t)B_ * DIM_ * sizeof(float), hipMemcpyDeviceToDevice, stream);

    k_prep_wq<<<256, 256, 0, stream>>>(wq1, wq2, lq1g, lq2g, wqt);
    k_qbias<<<16, 256, 0, stream>>>(wq1, wq2, lq1b, lq2b, qbias);
    k_f2bf<<<512, 256, 0, stream>>>(wf, wfb, 131072);
    k_kvlnt<<<2048, 256, 0, stream>>>(tf, lkvg, lkvb, kvn, kvt);
    k_xln<<<BT_, 256, 0, stream>>>(x, xn);
    k_qgemm<<<2304, 256, 0, stream>>>(xn, wqt, qbias, qbuf);
    hipMemsetAsync(denom, 0, (size_t)2 * BT_ * 4, stream);
    hipMemsetAsync(avgs, 0, (size_t)BT_ * 4, stream);
    hipMemsetAsync(maxe, 0, (size_t)BT_ * 4, stream);
    // branch 0
    k_score<<<3072, 256, 0, stream>>>(qbuf, kvn, Pm, denom, 0);
    k_pv<<<1536, 256, 0, stream>>>(Pm, kvt, denom, ob, avgs, maxe, 0);
    // branch 1 (P buffer reused; stream-ordered)
    k_score<<<3072, 256, 0, stream>>>(qbuf, kvn, Pm, denom, 1);
    k_pv<<<1536, 256, 0, stream>>>(Pm, kvt, denom, ob, avgs, maxe, 1);
    k_xse<<<9216, 256, 0, stream>>>(ob, ob + (size_t)BT_ * TXT_, avgs, maxe, cdw, xse);
    k_fgemm<<<2304, 256, 0, stream>>>(xse, wfb, out);
}

// Round 5
// 636.918 us; speedup vs baseline: 1.2439x; 1.2439x over previous
//
#include <hip/hip_runtime.h>

// ---------------- problem constants ----------------
#define B_    64
#define TOK_  576
#define DIM_  1024
#define TXT_  512
#define NT_   1000
#define NTQ_  1024                 // kvn padded rows (zero-filled 1000..1023)
#define NTP_  1024                 // kvt padded cols / P padded cols
#define H_    24
#define BT_   (B_ * TOK_)          // 36864 rows
static constexpr float SCALE_ = 0.0441941738241592f;   // 512^-0.5

typedef __bf16 bf16x8 __attribute__((ext_vector_type(8)));
typedef float  f32x4  __attribute__((ext_vector_type(4)));

__device__ __forceinline__ unsigned short f2bf(float f) {
    unsigned u = __float_as_uint(f);
    u += 0x7fffu + ((u >> 16) & 1u);
    return (unsigned short)(u >> 16);
}
__device__ __forceinline__ float bf2f(unsigned short h) {
    return __uint_as_float(((unsigned)h) << 16);
}
__device__ __forceinline__ f32x4 mfma16(bf16x8 a, bf16x8 b, f32x4 c) {
    return __builtin_amdgcn_mfma_f32_16x16x32_bf16(a, b, c, 0, 0, 0);
}
__device__ __forceinline__ void unpack8(uint4 v, float* f) {
    unsigned a0 = v.x, a1 = v.y, a2 = v.z, a3 = v.w;
    f[0] = bf2f((unsigned short)(a0 & 0xffff)); f[1] = bf2f((unsigned short)(a0 >> 16));
    f[2] = bf2f((unsigned short)(a1 & 0xffff)); f[3] = bf2f((unsigned short)(a1 >> 16));
    f[4] = bf2f((unsigned short)(a2 & 0xffff)); f[5] = bf2f((unsigned short)(a2 >> 16));
    f[6] = bf2f((unsigned short)(a3 & 0xffff)); f[7] = bf2f((unsigned short)(a3 >> 16));
}
// order-preserving float->uint encoding for atomicMax over signed floats
__device__ __forceinline__ unsigned encmax(float f) {
    unsigned u = __float_as_uint(f);
    return (u & 0x80000000u) ? ~u : (u | 0x80000000u);
}
__device__ __forceinline__ float decmax(unsigned k) {
    unsigned u = (k & 0x80000000u) ? (k ^ 0x80000000u) : ~k;
    return __uint_as_float(u);
}

// async global->LDS, 16B per lane; lds base wave-uniform, lanes land at base + lane*16
typedef const __attribute__((address_space(1))) unsigned int* as1_u32p;
typedef __attribute__((address_space(3))) unsigned int* as3_u32p;
__device__ __forceinline__ void gll16(const void* g, void* l) {
    __builtin_amdgcn_global_load_lds((as1_u32p)g, (as3_u32p)l, 16, 0, 0);
}

// ---------------- weight prep ----------------
// Wq (1024x512 f32), rows pre-scaled by LN gamma -> WqT bf16 [branch][512][1024]
__global__ void k_prep_wq(const float* __restrict__ wq1, const float* __restrict__ wq2,
                          const float* __restrict__ g1, const float* __restrict__ g2,
                          unsigned short* __restrict__ wqt) {
    __shared__ float tile[64][68];
    int bx = blockIdx.x, t = threadIdx.x;
    int br = bx >> 7, kt = (bx >> 3) & 15, nt = bx & 7;
    const float* wq = br ? wq2 : wq1;
    const float* gg = br ? g2 : g1;
#pragma unroll
    for (int i = 0; i < 4; ++i) {
        int idx4 = t + i * 256;
        int kl = idx4 >> 4, n4 = (idx4 & 15) * 4;
        float gv = gg[kt * 64 + kl];
        float4 v = *reinterpret_cast<const float4*>(wq + (size_t)(kt * 64 + kl) * 512 + nt * 64 + n4);
        tile[kl][n4 + 0] = v.x * gv; tile[kl][n4 + 1] = v.y * gv;
        tile[kl][n4 + 2] = v.z * gv; tile[kl][n4 + 3] = v.w * gv;
    }
    __syncthreads();
#pragma unroll
    for (int i = 0; i < 4; ++i) {
        int idx4 = t + i * 256;
        int nl = idx4 >> 4, k4 = (idx4 & 15) * 4;
        ushort4 o = make_ushort4(f2bf(tile[k4 + 0][nl]), f2bf(tile[k4 + 1][nl]),
                                 f2bf(tile[k4 + 2][nl]), f2bf(tile[k4 + 3][nl]));
        *reinterpret_cast<ushort4*>(wqt + (size_t)br * 512 * 1024 + (size_t)(nt * 64 + nl) * 1024 + kt * 64 + k4) = o;
    }
}

// qbias[br][e] = sum_d beta[d] * Wq[d][e]
__global__ void k_qbias(const float* __restrict__ wq1, const float* __restrict__ wq2,
                        const float* __restrict__ b1, const float* __restrict__ b2,
                        float* __restrict__ qbias) {
    int br = blockIdx.x >> 3, e0 = (blockIdx.x & 7) * 64;
    int t = threadIdx.x;
    int e = e0 + (t & 63), part = t >> 6;
    const float* wq = br ? wq2 : wq1;
    const float* bb = br ? b2 : b1;
    float s = 0.f;
    for (int d = part * 256; d < part * 256 + 256; ++d) s += bb[d] * wq[(size_t)d * 512 + e];
    __shared__ float red[256];
    red[t] = s;
    __syncthreads();
    if (t < 64) qbias[br * 512 + e0 + t] = red[t] + red[64 + t] + red[128 + t] + red[192 + t];
}

__global__ void k_f2bf(const float* __restrict__ src, unsigned short* __restrict__ dst, int n4) {
    int i = blockIdx.x * blockDim.x + threadIdx.x;
    if (i < n4) {
        float4 v = *reinterpret_cast<const float4*>(src + (size_t)i * 4);
        ushort4 o = make_ushort4(f2bf(v.x), f2bf(v.y), f2bf(v.z), f2bf(v.w));
        *reinterpret_cast<ushort4*>(dst + (size_t)i * 4) = o;
    }
}

// ---------------- kv layernorm:  text_fea (NT,B,TXT) -> kvn bf16 [b][n_pad1024][e] ----------------
__global__ void k_kvln(const float* __restrict__ tf, const float* __restrict__ g,
                       const float* __restrict__ bta, unsigned short* __restrict__ kvn) {
    int row = blockIdx.x;                 // b*1024 + n
    int b = row >> 10, n = row & 1023;
    int t = threadIdx.x;                  // 128 threads, 4 elems each
    unsigned short* dst = kvn + ((size_t)b * NTQ_ + n) * TXT_;
    if (n >= NT_) {                       // zero-pad rows
        *reinterpret_cast<ushort4*>(dst + t * 4) = make_ushort4(0, 0, 0, 0);
        return;
    }
    const float* src = tf + ((size_t)n * B_ + b) * TXT_;
    float4 v = *reinterpret_cast<const float4*>(src + t * 4);
    float s = v.x + v.y + v.z + v.w;
    float ss = v.x * v.x + v.y * v.y + v.z * v.z + v.w * v.w;
#pragma unroll
    for (int d = 1; d < 64; d <<= 1) { s += __shfl_xor(s, d); ss += __shfl_xor(ss, d); }
    __shared__ float red[4];
    if ((t & 63) == 0) { red[(t >> 6) * 2] = s; red[(t >> 6) * 2 + 1] = ss; }
    __syncthreads();
    s = red[0] + red[2]; ss = red[1] + red[3];
    float m = s * (1.f / TXT_);
    float rs = rsqrtf(ss * (1.f / TXT_) - m * m + 1e-5f);
    int d0 = t * 4;
    ushort4 o = make_ushort4(f2bf((v.x - m) * rs * g[d0 + 0] + bta[d0 + 0]),
                             f2bf((v.y - m) * rs * g[d0 + 1] + bta[d0 + 1]),
                             f2bf((v.z - m) * rs * g[d0 + 2] + bta[d0 + 2]),
                             f2bf((v.w - m) * rs * g[d0 + 3] + bta[d0 + 3]));
    *reinterpret_cast<ushort4*>(dst + d0) = o;
}

// ---------------- kv transpose:  kvn [b][n][e] -> kvt [b][e][n_pad1024] ----------------
__global__ void k_kvt(const unsigned short* __restrict__ kvn, unsigned short* __restrict__ kvt) {
    __shared__ unsigned short tile[64][68];
    int bx = blockIdx.x;
    int b = bx >> 7, rem = bx & 127, et = rem >> 4, nt = rem & 15;
    int t = threadIdx.x;
#pragma unroll
    for (int i = 0; i < 4; ++i) {
        int idx4 = t + i * 256;
        int nl = idx4 >> 4, e4 = (idx4 & 15) * 4;
        int ng = nt * 64 + nl;
        ushort4 v = make_ushort4(0, 0, 0, 0);
        if (ng < NT_) v = *reinterpret_cast<const ushort4*>(kvn + ((size_t)b * NTQ_ + ng) * TXT_ + et * 64 + e4);
        tile[nl][e4 + 0] = v.x; tile[nl][e4 + 1] = v.y; tile[nl][e4 + 2] = v.z; tile[nl][e4 + 3] = v.w;
    }
    __syncthreads();
#pragma unroll
    for (int i = 0; i < 4; ++i) {
        int idx4 = t + i * 256;
        int el = idx4 >> 4, n4 = (idx4 & 15) * 4;
        ushort4 o = make_ushort4(tile[n4 + 0][el], tile[n4 + 1][el], tile[n4 + 2][el], tile[n4 + 3][el]);
        *reinterpret_cast<ushort4*>(kvt + ((size_t)b * TXT_ + et * 64 + el) * NTP_ + nt * 64 + n4) = o;
    }
}

// ---------------- x layernorm (normalized only; gamma/beta folded into Wq) ----------------
__global__ void k_xln(const float* __restrict__ x, unsigned short* __restrict__ xn) {
    int bt = blockIdx.x;                   // b*TOK + t
    int b = bt / TOK_, tk = bt - b * TOK_;
    const float* src = x + ((size_t)(tk + 1) * B_ + b) * DIM_;
    int t = threadIdx.x;                   // 256 threads, 4 floats each
    float4 v = *reinterpret_cast<const float4*>(src + t * 4);
    float s = v.x + v.y + v.z + v.w;
    float ss = v.x * v.x + v.y * v.y + v.z * v.z + v.w * v.w;
#pragma unroll
    for (int d = 1; d < 64; d <<= 1) { s += __shfl_xor(s, d); ss += __shfl_xor(ss, d); }
    __shared__ float red[8];
    if ((t & 63) == 0) { red[t >> 6] = s; red[4 + (t >> 6)] = ss; }
    __syncthreads();
    s = red[0] + red[1] + red[2] + red[3];
    ss = red[4] + red[5] + red[6] + red[7];
    float m = s * (1.f / DIM_);
    float rs = rsqrtf(ss * (1.f / DIM_) - m * m + 1e-5f);
    int d0 = t * 4;
    ushort4 o = make_ushort4(f2bf((v.x - m) * rs), f2bf((v.y - m) * rs),
                             f2bf((v.z - m) * rs), f2bf((v.w - m) * rs));
    *reinterpret_cast<ushort4*>(xn + (size_t)bt * DIM_ + d0) = o;
}

// ---------------- 128x128xK bf16 GEMM mainloop, global_load_lds staging (m97 structure) ----------------
// A:[M][K], B:[N][K], both k-contiguous.
__device__ __forceinline__ void gemm_loop_gll(const unsigned short* __restrict__ A,
                                              const unsigned short* __restrict__ Bp,
                                              int K, unsigned short* a_lds, unsigned short* b_lds,
                                              int tid, f32x4 acc[4][4]) {
    const int l = tid & 63, w = tid >> 6;
    const int l16 = l & 15, lg = l >> 4;
    const int wm = w & 1, wn = w >> 1;
    const f32x4 fz = {0.f, 0.f, 0.f, 0.f};
#pragma unroll
    for (int mt = 0; mt < 4; ++mt)
#pragma unroll
        for (int nt = 0; nt < 4; ++nt) acc[mt][nt] = fz;
    const int lrow = l >> 3;               // 0..7
    const int k8g = (l & 7) ^ lrow;        // pre-swizzled source granule
    const int nk = K >> 6;
    for (int kt = 0; kt < nk; ++kt) {
#pragma unroll
        for (int i = 0; i < 4; ++i) {
            int row = i * 32 + w * 8 + lrow;
            gll16(A + (size_t)row * K + kt * 64 + k8g * 8, &a_lds[(i * 256 + w * 64) * 8]);
        }
#pragma unroll
        for (int i = 0; i < 4; ++i) {
            int row = i * 32 + w * 8 + lrow;
            gll16(Bp + (size_t)row * K + kt * 64 + k8g * 8, &b_lds[(i * 256 + w * 64) * 8]);
        }
        __syncthreads();
#pragma unroll
        for (int kk = 0; kk < 2; ++kk) {
            bf16x8 af[4], bff[4];
#pragma unroll
            for (int mt = 0; mt < 4; ++mt) {
                int row = wm * 64 + mt * 16 + l16;
                int gs = (kk * 4 + lg) ^ (row & 7);
                af[mt] = *reinterpret_cast<const bf16x8*>(a_lds + row * 64 + gs * 8);
            }
#pragma unroll
            for (int nt = 0; nt < 4; ++nt) {
                int row = wn * 64 + nt * 16 + l16;
                int gs = (kk * 4 + lg) ^ (row & 7);
                bff[nt] = *reinterpret_cast<const bf16x8*>(b_lds + row * 64 + gs * 8);
            }
#pragma unroll
            for (int mt = 0; mt < 4; ++mt)
#pragma unroll
                for (int nt = 0; nt < 4; ++nt)
                    acc[mt][nt] = mfma16(af[mt], bff[nt], acc[mt][nt]);
        }
        __syncthreads();
    }
}

// ---------------- 96x128xK variant (M-tile 96 keeps tiles inside one b: 576 = 6*96) ----------------
__device__ __forceinline__ void gemm_loop96(const unsigned short* __restrict__ A,
                                            const unsigned short* __restrict__ Bp,
                                            int K, unsigned short* a_lds, unsigned short* b_lds,
                                            int tid, f32x4 acc[3][4]) {
    const int l = tid & 63, w = tid >> 6;
    const int l16 = l & 15, lg = l >> 4;
    const int wm = w & 1, wn = w >> 1;
    const f32x4 fz = {0.f, 0.f, 0.f, 0.f};
#pragma unroll
    for (int mt = 0; mt < 3; ++mt)
#pragma unroll
        for (int nt = 0; nt < 4; ++nt) acc[mt][nt] = fz;
    const int lrow = l >> 3;
    const int k8g = (l & 7) ^ lrow;
    const int nk = K >> 6;
    for (int kt = 0; kt < nk; ++kt) {
#pragma unroll
        for (int i = 0; i < 3; ++i) {
            int row = i * 32 + w * 8 + lrow;
            gll16(A + (size_t)row * K + kt * 64 + k8g * 8, &a_lds[(i * 256 + w * 64) * 8]);
        }
#pragma unroll
        for (int i = 0; i < 4; ++i) {
            int row = i * 32 + w * 8 + lrow;
            gll16(Bp + (size_t)row * K + kt * 64 + k8g * 8, &b_lds[(i * 256 + w * 64) * 8]);
        }
        __syncthreads();
#pragma unroll
        for (int kk = 0; kk < 2; ++kk) {
            bf16x8 af[3], bff[4];
#pragma unroll
            for (int mt = 0; mt < 3; ++mt) {
                int row = wm * 48 + mt * 16 + l16;
                int gs = (kk * 4 + lg) ^ (row & 7);
                af[mt] = *reinterpret_cast<const bf16x8*>(a_lds + row * 64 + gs * 8);
            }
#pragma unroll
            for (int nt = 0; nt < 4; ++nt) {
                int row = wn * 64 + nt * 16 + l16;
                int gs = (kk * 4 + lg) ^ (row & 7);
                bff[nt] = *reinterpret_cast<const bf16x8*>(b_lds + row * 64 + gs * 8);
            }
#pragma unroll
            for (int mt = 0; mt < 3; ++mt)
#pragma unroll
                for (int nt = 0; nt < 4; ++nt)
                    acc[mt][nt] = mfma16(af[mt], bff[nt], acc[mt][nt]);
        }
        __syncthreads();
    }
}

// q GEMM:  q[br] = (xn @ (diag(g)Wq[br])^T + bias) * SCALE  -> bf16 (36864x512)
__global__ __launch_bounds__(256, 4) void k_qgemm(const unsigned short* __restrict__ xn,
                                                  const unsigned short* __restrict__ wqt,
                                                  const float* __restrict__ qbias,
                                                  unsigned short* __restrict__ qb) {
    int bid = blockIdx.x;                        // 2304 = 4bn x 288bm x 2br
    int vb = (bid & 7) * 288 + (bid >> 3);       // XCD-contiguous
    int bn = vb & 3;
    int t = vb >> 2;
    int br = (t >= 288) ? 1 : 0;
    int bm = t - br * 288;
    const unsigned short* A = xn + (size_t)bm * 128 * DIM_;
    const unsigned short* Bp = wqt + (size_t)br * 512 * 1024 + (size_t)bn * 128 * 1024;
    unsigned short* C = qb + (size_t)br * BT_ * TXT_;
    const float* bias = qbias + br * 512;
    __shared__ unsigned short a_lds[128 * 64];
    __shared__ unsigned short b_lds[128 * 64];
    f32x4 acc[4][4];
    gemm_loop_gll(A, Bp, DIM_, a_lds, b_lds, threadIdx.x, acc);
    const int l = threadIdx.x & 63, w = threadIdx.x >> 6;
    const int l16 = l & 15, lg = l >> 4, wm = w & 1, wn = w >> 1;
#pragma unroll
    for (int mt = 0; mt < 4; ++mt)
#pragma unroll
        for (int nt = 0; nt < 4; ++nt) {
            int col = bn * 128 + wn * 64 + nt * 16 + l16;
            float bv = bias[col];
#pragma unroll
            for (int r = 0; r < 4; ++r) {
                int row = bm * 128 + wm * 64 + mt * 16 + lg * 4 + r;
                C[(size_t)row * TXT_ + col] = f2bf((acc[mt][nt][r] + bv) * SCALE_);
            }
        }
}

// score GEMM: P = exp(q @ kvn^T) per branch, + row-sum atomics into denom
__global__ __launch_bounds__(256, 4) void k_score(const unsigned short* __restrict__ qbuf,
                                                  const unsigned short* __restrict__ kvn,
                                                  unsigned short* __restrict__ P,
                                                  float* __restrict__ denom, int br) {
    int bid = blockIdx.x;                        // 3072 = 64b x 6mt x 8nt
    int vb = (bid & 7) * 384 + (bid >> 3);       // XCD-contiguous, 8 b's per XCD
    int tile = vb % 48, b = vb / 48;
    int mt = tile >> 3, nt = tile & 7;
    const unsigned short* A = qbuf + ((size_t)br * BT_ + (size_t)b * TOK_ + mt * 96) * TXT_;
    const unsigned short* Bp = kvn + (size_t)b * NTQ_ * TXT_ + (size_t)nt * 128 * TXT_;
    __shared__ unsigned short a_lds[96 * 64];
    __shared__ unsigned short b_lds[128 * 64];
    f32x4 acc[3][4];
    gemm_loop96(A, Bp, TXT_, a_lds, b_lds, threadIdx.x, acc);
    const int l = threadIdx.x & 63, w = threadIdx.x >> 6;
    const int l16 = l & 15, lg = l >> 4, wm = w & 1, wn = w >> 1;
    float* dn = denom + (size_t)br * BT_;
#pragma unroll
    for (int mt2 = 0; mt2 < 3; ++mt2)
#pragma unroll
        for (int r = 0; r < 4; ++r) {
            int row = b * TOK_ + mt * 96 + wm * 48 + mt2 * 16 + lg * 4 + r;
            float s = 0.f;
#pragma unroll
            for (int nt2 = 0; nt2 < 4; ++nt2) {
                int col = nt * 128 + wn * 64 + nt2 * 16 + l16;
                float p = (col < NT_) ? __expf(acc[mt2][nt2][r]) : 0.f;
                s += p;
                P[(size_t)row * NTP_ + col] = f2bf(p);
            }
#pragma unroll
            for (int d = 1; d < 16; d <<= 1) s += __shfl_xor(s, d);
            if (l16 == 0) atomicAdd(&dn[row], s);
        }
}

// PV GEMM: O = (P @ kvt^T) / denom -> bf16; fused per-row sum (br0) / max (br1) atomics
__global__ __launch_bounds__(256, 4) void k_pv(const unsigned short* __restrict__ P,
                                               const unsigned short* __restrict__ kvt,
                                               const float* __restrict__ denom,
                                               unsigned short* __restrict__ ob,
                                               float* __restrict__ avgs,
                                               unsigned* __restrict__ maxe, int br) {
    int bid = blockIdx.x;                        // 1536 = 64b x 6mt x 4nt
    int vb = (bid & 7) * 192 + (bid >> 3);       // XCD-contiguous, 8 b's per XCD
    int tile = vb % 24, b = vb / 24;
    int mt = tile >> 2, nt = tile & 3;
    const unsigned short* A = P + ((size_t)b * TOK_ + mt * 96) * NTP_;
    const unsigned short* Bp = kvt + (size_t)b * TXT_ * NTP_ + (size_t)nt * 128 * NTP_;
    __shared__ unsigned short a_lds[96 * 64];
    __shared__ unsigned short b_lds[128 * 64];
    f32x4 acc[3][4];
    gemm_loop96(A, Bp, NTP_, a_lds, b_lds, threadIdx.x, acc);
    const int l = threadIdx.x & 63, w = threadIdx.x >> 6;
    const int l16 = l & 15, lg = l >> 4, wm = w & 1, wn = w >> 1;
    const float* dn = denom + (size_t)br * BT_;
#pragma unroll
    for (int mt2 = 0; mt2 < 3; ++mt2)
#pragma unroll
        for (int r = 0; r < 4; ++r) {
            int row = b * TOK_ + mt * 96 + wm * 48 + mt2 * 16 + lg * 4 + r;
            float inv = 1.f / dn[row];
            unsigned short* dst = ob + ((size_t)br * BT_ + row) * TXT_;
            float sum = 0.f, mx = -1e30f;
#pragma unroll
            for (int nt2 = 0; nt2 < 4; ++nt2) {
                int col = nt * 128 + wn * 64 + nt2 * 16 + l16;
                float o = acc[mt2][nt2][r] * inv;
                dst[col] = f2bf(o);
                sum += o;
                mx = fmaxf(mx, o);
            }
#pragma unroll
            for (int d = 1; d < 16; d <<= 1) {
                sum += __shfl_xor(sum, d);
                mx = fmaxf(mx, __shfl_xor(mx, d));
            }
            if (l16 == 0) {
                if (br == 0) atomicAdd(&avgs[row], sum);
                else         atomicMax(&maxe[row], encmax(mx));
            }
        }
}

// final GEMM: y = xse (36864x512) @ Wf^T (1024x512) -> fp32 scattered into out layout
__global__ __launch_bounds__(256, 4) void k_fgemm(const unsigned short* __restrict__ xse,
                                                  const unsigned short* __restrict__ wfb,
                                                  float* __restrict__ out) {
    int bid = blockIdx.x;                        // 2304 = 8bn x 288bm
    int vb = (bid & 7) * 288 + (bid >> 3);
    int bn = vb & 7, bm = vb >> 3;
    const unsigned short* A = xse + (size_t)bm * 128 * TXT_;
    const unsigned short* Bp = wfb + (size_t)bn * 128 * TXT_;
    __shared__ unsigned short a_lds[128 * 64];
    __shared__ unsigned short b_lds[128 * 64];
    f32x4 acc[4][4];
    gemm_loop_gll(A, Bp, TXT_, a_lds, b_lds, threadIdx.x, acc);
    const int l = threadIdx.x & 63, w = threadIdx.x >> 6;
    const int l16 = l & 15, lg = l >> 4, wm = w & 1, wn = w >> 1;
#pragma unroll
    for (int mt = 0; mt < 4; ++mt)
#pragma unroll
        for (int r = 0; r < 4; ++r) {
            int rowg = bm * 128 + wm * 64 + mt * 16 + lg * 4 + r;
            int b = rowg / TOK_, tk = rowg - b * TOK_;
            float* dst = out + ((size_t)(tk + 1) * B_ + b) * DIM_;
#pragma unroll
            for (int nt = 0; nt < 4; ++nt) {
                int col = bn * 128 + wn * 64 + nt * 16 + l16;
                dst[col] = acc[mt][nt][r];
            }
        }
}

// ---------------- x_se = o1*g1 + o2*g2 -> bf16, with gate conv fused (lane 0 per row) ----------------
__global__ void k_xse(const unsigned short* __restrict__ o1, const unsigned short* __restrict__ o2,
                      const float* __restrict__ avgs, const unsigned* __restrict__ maxe,
                      const float* __restrict__ cdw, unsigned short* __restrict__ xse) {
    int idx8 = blockIdx.x * 256 + threadIdx.x;    // < 36864*64
    int bt = idx8 >> 6, e8 = threadIdx.x & 63;
    float gg1 = 0.f, gg2 = 0.f;
    if (e8 == 0) {
        int b = bt / TOK_, hw = bt - b * TOK_, h = hw / H_, ww = hw - h * H_;
        float a1 = 0.f, a2 = 0.f;
#pragma unroll
        for (int ky = 0; ky < 3; ++ky)
#pragma unroll
            for (int kx = 0; kx < 3; ++kx) {
                int hh = h + ky - 1, wx = ww + kx - 1;
                if (hh >= 0 && hh < H_ && wx >= 0 && wx < H_) {
                    float wv = cdw[ky * 3 + kx];
                    int s = b * TOK_ + hh * H_ + wx;
                    a1 += wv * avgs[s] * (1.f / TXT_);
                    a2 += wv * decmax(maxe[s]);
                }
            }
        gg1 = 1.f / (1.f + __expf(-a1));
        gg2 = 1.f / (1.f + __expf(-a2));
    }
    gg1 = __shfl(gg1, 0);
    gg2 = __shfl(gg2, 0);
    float f1[8], f2[8];
    unpack8(*reinterpret_cast<const uint4*>(o1 + (size_t)bt * TXT_ + e8 * 8), f1);
    unpack8(*reinterpret_cast<const uint4*>(o2 + (size_t)bt * TXT_ + e8 * 8), f2);
    unsigned r[4];
#pragma unroll
    for (int j = 0; j < 4; ++j) {
        unsigned lo = f2bf(f1[2 * j] * gg1 + f2[2 * j] * gg2);
        unsigned hi = f2bf(f1[2 * j + 1] * gg1 + f2[2 * j + 1] * gg2);
        r[j] = lo | (hi << 16);
    }
    uint4 o = make_uint4(r[0], r[1], r[2], r[3]);
    *reinterpret_cast<uint4*>(xse + (size_t)bt * TXT_ + e8 * 8) = o;
}

// ---------------- launcher ----------------
extern "C" void kernel_launch(void* const* d_in, const int* in_sizes, int n_in,
                              void* d_out, int out_size, void* d_ws, size_t ws_size,
                              hipStream_t stream) {
    (void)in_sizes; (void)n_in; (void)out_size; (void)ws_size;
    const float* x    = (const float*)d_in[0];
    const float* tf   = (const float*)d_in[1];
    const float* lq1g = (const float*)d_in[2];
    const float* lq1b = (const float*)d_in[3];
    const float* lq2g = (const float*)d_in[4];
    const float* lq2b = (const float*)d_in[5];
    const float* lkvg = (const float*)d_in[6];
    const float* lkvb = (const float*)d_in[7];
    const float* wq1  = (const float*)d_in[8];
    const float* wq2  = (const float*)d_in[9];
    const float* cdw  = (const float*)d_in[10];
    const float* wf   = (const float*)d_in[11];
    float* out = (float*)d_out;

    char* ws = (char*)d_ws;
    size_t off = 0;
    auto carve = [&](size_t bytes) { char* p = ws + off; off += (bytes + 255) & ~(size_t)255; return p; };
    unsigned short* kvn  = (unsigned short*)carve((size_t)B_ * NTQ_ * TXT_ * 2);       // 67.1 MB
    unsigned short* kvt  = (unsigned short*)carve((size_t)B_ * TXT_ * NTP_ * 2);       // 67.1 MB
    unsigned short* wqt  = (unsigned short*)carve((size_t)2 * 512 * 1024 * 2);         // 2 MB
    unsigned short* wfb  = (unsigned short*)carve((size_t)1024 * 512 * 2);             // 1 MB
    float* qbias = (float*)carve((size_t)2 * 512 * 4);
    float* denom = (float*)carve((size_t)2 * BT_ * 4);                                 // 0.3 MB
    float* avgs  = (float*)carve((size_t)BT_ * 4);
    unsigned* maxe = (unsigned*)carve((size_t)BT_ * 4);
    unsigned short* xn   = (unsigned short*)carve((size_t)BT_ * DIM_ * 2);             // 75.5 MB
    unsigned short* qbuf = (unsigned short*)carve((size_t)2 * BT_ * TXT_ * 2);         // 75.5 MB
    unsigned short* ob   = (unsigned short*)carve((size_t)2 * BT_ * TXT_ * 2);         // 75.5 MB
    unsigned short* Pm   = xn;     // P (36864x1024 bf16, per branch): xn dead after k_qgemm
    unsigned short* xse  = qbuf;   // safe: qbuf dead after last k_score

    // row 0 of output = x_cls
    hipMemcpyAsync(out, x, (size_t)B_ * DIM_ * sizeof(float), hipMemcpyDeviceToDevice, stream);

    k_prep_wq<<<256, 256, 0, stream>>>(wq1, wq2, lq1g, lq2g, wqt);
    k_qbias<<<16, 256, 0, stream>>>(wq1, wq2, lq1b, lq2b, qbias);
    k_f2bf<<<512, 256, 0, stream>>>(wf, wfb, 131072);
    k_kvln<<<B_ * NTQ_, 128, 0, stream>>>(tf, lkvg, lkvb, kvn);
    k_kvt<<<8192, 256, 0, stream>>>(kvn, kvt);
    k_xln<<<BT_, 256, 0, stream>>>(x, xn);
    k_qgemm<<<2304, 256, 0, stream>>>(xn, wqt, qbias, qbuf);
    hipMemsetAsync(denom, 0, (size_t)2 * BT_ * 4, stream);
    hipMemsetAsync(avgs, 0, (size_t)BT_ * 4, stream);
    hipMemsetAsync(maxe, 0, (size_t)BT_ * 4, stream);
    // branch 0
    k_score<<<3072, 256, 0, stream>>>(qbuf, kvn, Pm, denom, 0);
    k_pv<<<1536, 256, 0, stream>>>(Pm, kvt, denom, ob, avgs, maxe, 0);
    // branch 1 (P buffer reused; stream-ordered)
    k_score<<<3072, 256, 0, stream>>>(qbuf, kvn, Pm, denom, 1);
    k_pv<<<1536, 256, 0, stream>>>(Pm, kvt, denom, ob, avgs, maxe, 1);
    k_xse<<<9216, 256, 0, stream>>>(ob, ob + (size_t)BT_ * TXT_, avgs, maxe, cdw, xse);
    k_fgemm<<<2304, 256, 0, stream>>>(xse, wfb, out);
}

// Round 6
// 635.277 us; speedup vs baseline: 1.2471x; 1.0026x over previous
//
#include <hip/hip_runtime.h>

// ---------------- problem constants ----------------
#define B_    64
#define TOK_  576
#define DIM_  1024
#define TXT_  512
#define NT_   1000
#define NTQ_  1024                 // kvn padded rows (zero-filled 1000..1023)
#define NTP_  1024                 // kvt padded cols / P padded cols
#define H_    24
#define BT_   (B_ * TOK_)          // 36864 rows
static constexpr float SCALE_ = 0.0441941738241592f;   // 512^-0.5

typedef __bf16 bf16x8 __attribute__((ext_vector_type(8)));
typedef float  f32x4  __attribute__((ext_vector_type(4)));

__device__ __forceinline__ unsigned short f2bf(float f) {
    unsigned u = __float_as_uint(f);
    u += 0x7fffu + ((u >> 16) & 1u);
    return (unsigned short)(u >> 16);
}
__device__ __forceinline__ float bf2f(unsigned short h) {
    return __uint_as_float(((unsigned)h) << 16);
}
__device__ __forceinline__ f32x4 mfma16(bf16x8 a, bf16x8 b, f32x4 c) {
    return __builtin_amdgcn_mfma_f32_16x16x32_bf16(a, b, c, 0, 0, 0);
}
__device__ __forceinline__ void unpack8(uint4 v, float* f) {
    unsigned a0 = v.x, a1 = v.y, a2 = v.z, a3 = v.w;
    f[0] = bf2f((unsigned short)(a0 & 0xffff)); f[1] = bf2f((unsigned short)(a0 >> 16));
    f[2] = bf2f((unsigned short)(a1 & 0xffff)); f[3] = bf2f((unsigned short)(a1 >> 16));
    f[4] = bf2f((unsigned short)(a2 & 0xffff)); f[5] = bf2f((unsigned short)(a2 >> 16));
    f[6] = bf2f((unsigned short)(a3 & 0xffff)); f[7] = bf2f((unsigned short)(a3 >> 16));
}
// order-preserving float->uint encoding for atomicMax over signed floats
__device__ __forceinline__ unsigned encmax(float f) {
    unsigned u = __float_as_uint(f);
    return (u & 0x80000000u) ? ~u : (u | 0x80000000u);
}
__device__ __forceinline__ float decmax(unsigned k) {
    unsigned u = (k & 0x80000000u) ? (k ^ 0x80000000u) : ~k;
    return __uint_as_float(u);
}

// async global->LDS, 16B per lane; lds base wave-uniform, lanes land at base + lane*16
typedef const __attribute__((address_space(1))) unsigned int* as1_u32p;
typedef __attribute__((address_space(3))) unsigned int* as3_u32p;
__device__ __forceinline__ void gll16(const void* g, void* l) {
    __builtin_amdgcn_global_load_lds((as1_u32p)g, (as3_u32p)l, 16, 0, 0);
}

// ---------------- weight prep ----------------
// Wq (1024x512 f32), rows pre-scaled by LN gamma -> WqT bf16 [branch][512][1024]
__global__ void k_prep_wq(const float* __restrict__ wq1, const float* __restrict__ wq2,
                          const float* __restrict__ g1, const float* __restrict__ g2,
                          unsigned short* __restrict__ wqt) {
    __shared__ float tile[64][68];
    int bx = blockIdx.x, t = threadIdx.x;
    int br = bx >> 7, kt = (bx >> 3) & 15, nt = bx & 7;
    const float* wq = br ? wq2 : wq1;
    const float* gg = br ? g2 : g1;
#pragma unroll
    for (int i = 0; i < 4; ++i) {
        int idx4 = t + i * 256;
        int kl = idx4 >> 4, n4 = (idx4 & 15) * 4;
        float gv = gg[kt * 64 + kl];
        float4 v = *reinterpret_cast<const float4*>(wq + (size_t)(kt * 64 + kl) * 512 + nt * 64 + n4);
        tile[kl][n4 + 0] = v.x * gv; tile[kl][n4 + 1] = v.y * gv;
        tile[kl][n4 + 2] = v.z * gv; tile[kl][n4 + 3] = v.w * gv;
    }
    __syncthreads();
#pragma unroll
    for (int i = 0; i < 4; ++i) {
        int idx4 = t + i * 256;
        int nl = idx4 >> 4, k4 = (idx4 & 15) * 4;
        ushort4 o = make_ushort4(f2bf(tile[k4 + 0][nl]), f2bf(tile[k4 + 1][nl]),
                                 f2bf(tile[k4 + 2][nl]), f2bf(tile[k4 + 3][nl]));
        *reinterpret_cast<ushort4*>(wqt + (size_t)br * 512 * 1024 + (size_t)(nt * 64 + nl) * 1024 + kt * 64 + k4) = o;
    }
}

// qbias[br][e] = sum_d beta[d] * Wq[d][e]
__global__ void k_qbias(const float* __restrict__ wq1, const float* __restrict__ wq2,
                        const float* __restrict__ b1, const float* __restrict__ b2,
                        float* __restrict__ qbias) {
    int br = blockIdx.x >> 3, e0 = (blockIdx.x & 7) * 64;
    int t = threadIdx.x;
    int e = e0 + (t & 63), part = t >> 6;
    const float* wq = br ? wq2 : wq1;
    const float* bb = br ? b2 : b1;
    float s = 0.f;
    for (int d = part * 256; d < part * 256 + 256; ++d) s += bb[d] * wq[(size_t)d * 512 + e];
    __shared__ float red[256];
    red[t] = s;
    __syncthreads();
    if (t < 64) qbias[br * 512 + e0 + t] = red[t] + red[64 + t] + red[128 + t] + red[192 + t];
}

__global__ void k_f2bf(const float* __restrict__ src, unsigned short* __restrict__ dst, int n4) {
    int i = blockIdx.x * blockDim.x + threadIdx.x;
    if (i < n4) {
        float4 v = *reinterpret_cast<const float4*>(src + (size_t)i * 4);
        ushort4 o = make_ushort4(f2bf(v.x), f2bf(v.y), f2bf(v.z), f2bf(v.w));
        *reinterpret_cast<ushort4*>(dst + (size_t)i * 4) = o;
    }
}

// ---------------- kv layernorm, wave-per-row: text_fea (NT,B,TXT) -> kvn bf16 [b][n_pad1024][e] ----------------
__global__ __launch_bounds__(512, 2) void k_kvln(const float* __restrict__ tf, const float* __restrict__ g,
                                                 const float* __restrict__ bta, unsigned short* __restrict__ kvn) {
    int row = blockIdx.x * 8 + (threadIdx.x >> 6);   // b*1024 + n
    int b = row >> 10, n = row & 1023;
    int l = threadIdx.x & 63;
    unsigned short* dst = kvn + ((size_t)b * NTQ_ + n) * TXT_ + l * 8;
    if (n >= NT_) {                                  // zero-pad rows
        *reinterpret_cast<uint4*>(dst) = make_uint4(0, 0, 0, 0);
        return;
    }
    const float* src = tf + ((size_t)n * B_ + b) * TXT_ + l * 8;
    float4 v0 = *reinterpret_cast<const float4*>(src);
    float4 v1 = *reinterpret_cast<const float4*>(src + 4);
    float s  = v0.x + v0.y + v0.z + v0.w + v1.x + v1.y + v1.z + v1.w;
    float ss = v0.x * v0.x + v0.y * v0.y + v0.z * v0.z + v0.w * v0.w
             + v1.x * v1.x + v1.y * v1.y + v1.z * v1.z + v1.w * v1.w;
#pragma unroll
    for (int d = 1; d < 64; d <<= 1) { s += __shfl_xor(s, d); ss += __shfl_xor(ss, d); }
    float m = s * (1.f / TXT_);
    float rs = rsqrtf(ss * (1.f / TXT_) - m * m + 1e-5f);
    float4 g0 = *reinterpret_cast<const float4*>(g + l * 8);
    float4 g1 = *reinterpret_cast<const float4*>(g + l * 8 + 4);
    float4 b0 = *reinterpret_cast<const float4*>(bta + l * 8);
    float4 b1 = *reinterpret_cast<const float4*>(bta + l * 8 + 4);
    unsigned r0 = (unsigned)f2bf((v0.x - m) * rs * g0.x + b0.x) | ((unsigned)f2bf((v0.y - m) * rs * g0.y + b0.y) << 16);
    unsigned r1 = (unsigned)f2bf((v0.z - m) * rs * g0.z + b0.z) | ((unsigned)f2bf((v0.w - m) * rs * g0.w + b0.w) << 16);
    unsigned r2 = (unsigned)f2bf((v1.x - m) * rs * g1.x + b1.x) | ((unsigned)f2bf((v1.y - m) * rs * g1.y + b1.y) << 16);
    unsigned r3 = (unsigned)f2bf((v1.z - m) * rs * g1.z + b1.z) | ((unsigned)f2bf((v1.w - m) * rs * g1.w + b1.w) << 16);
    *reinterpret_cast<uint4*>(dst) = make_uint4(r0, r1, r2, r3);
}

// ---------------- kv transpose:  kvn [b][n][e] -> kvt [b][e][n_pad1024] ----------------
__global__ void k_kvt(const unsigned short* __restrict__ kvn, unsigned short* __restrict__ kvt) {
    __shared__ unsigned short tile[64][68];
    int bx = blockIdx.x;
    int b = bx >> 7, rem = bx & 127, et = rem >> 4, nt = rem & 15;
    int t = threadIdx.x;
#pragma unroll
    for (int i = 0; i < 4; ++i) {
        int idx4 = t + i * 256;
        int nl = idx4 >> 4, e4 = (idx4 & 15) * 4;
        int ng = nt * 64 + nl;
        ushort4 v = make_ushort4(0, 0, 0, 0);
        if (ng < NT_) v = *reinterpret_cast<const ushort4*>(kvn + ((size_t)b * NTQ_ + ng) * TXT_ + et * 64 + e4);
        tile[nl][e4 + 0] = v.x; tile[nl][e4 + 1] = v.y; tile[nl][e4 + 2] = v.z; tile[nl][e4 + 3] = v.w;
    }
    __syncthreads();
#pragma unroll
    for (int i = 0; i < 4; ++i) {
        int idx4 = t + i * 256;
        int el = idx4 >> 4, n4 = (idx4 & 15) * 4;
        ushort4 o = make_ushort4(tile[n4 + 0][el], tile[n4 + 1][el], tile[n4 + 2][el], tile[n4 + 3][el]);
        *reinterpret_cast<ushort4*>(kvt + ((size_t)b * TXT_ + et * 64 + el) * NTP_ + nt * 64 + n4) = o;
    }
}

// ---------------- x layernorm, wave-per-row (normalized only; gamma/beta folded into Wq) ----------------
__global__ __launch_bounds__(512, 2) void k_xln(const float* __restrict__ x, unsigned short* __restrict__ xn) {
    int bt = blockIdx.x * 8 + (threadIdx.x >> 6);    // b*TOK + t
    int b = bt / TOK_, tk = bt - b * TOK_;
    int l = threadIdx.x & 63;
    const float* src = x + ((size_t)(tk + 1) * B_ + b) * DIM_ + l * 16;
    float4 v[4];
#pragma unroll
    for (int j = 0; j < 4; ++j) v[j] = *reinterpret_cast<const float4*>(src + j * 4);
    float s = 0.f, ss = 0.f;
#pragma unroll
    for (int j = 0; j < 4; ++j) {
        s += v[j].x + v[j].y + v[j].z + v[j].w;
        ss += v[j].x * v[j].x + v[j].y * v[j].y + v[j].z * v[j].z + v[j].w * v[j].w;
    }
#pragma unroll
    for (int d = 1; d < 64; d <<= 1) { s += __shfl_xor(s, d); ss += __shfl_xor(ss, d); }
    float m = s * (1.f / DIM_);
    float rs = rsqrtf(ss * (1.f / DIM_) - m * m + 1e-5f);
    unsigned short* dst = xn + (size_t)bt * DIM_ + l * 16;
#pragma unroll
    for (int h = 0; h < 2; ++h) {
        unsigned r0 = (unsigned)f2bf((v[2*h].x - m) * rs) | ((unsigned)f2bf((v[2*h].y - m) * rs) << 16);
        unsigned r1 = (unsigned)f2bf((v[2*h].z - m) * rs) | ((unsigned)f2bf((v[2*h].w - m) * rs) << 16);
        unsigned r2 = (unsigned)f2bf((v[2*h+1].x - m) * rs) | ((unsigned)f2bf((v[2*h+1].y - m) * rs) << 16);
        unsigned r3 = (unsigned)f2bf((v[2*h+1].z - m) * rs) | ((unsigned)f2bf((v[2*h+1].w - m) * rs) << 16);
        *reinterpret_cast<uint4*>(dst + h * 8) = make_uint4(r0, r1, r2, r3);
    }
}

// ---------------- 128x128xK bf16 GEMM mainloop, global_load_lds staging (m97 structure) ----------------
// A:[M][K], B:[N][K], both k-contiguous.
__device__ __forceinline__ void gemm_loop_gll(const unsigned short* __restrict__ A,
                                              const unsigned short* __restrict__ Bp,
                                              int K, unsigned short* a_lds, unsigned short* b_lds,
                                              int tid, f32x4 acc[4][4]) {
    const int l = tid & 63, w = tid >> 6;
    const int l16 = l & 15, lg = l >> 4;
    const int wm = w & 1, wn = w >> 1;
    const f32x4 fz = {0.f, 0.f, 0.f, 0.f};
#pragma unroll
    for (int mt = 0; mt < 4; ++mt)
#pragma unroll
        for (int nt = 0; nt < 4; ++nt) acc[mt][nt] = fz;
    const int lrow = l >> 3;               // 0..7
    const int k8g = (l & 7) ^ lrow;        // pre-swizzled source granule
    const int nk = K >> 6;
    for (int kt = 0; kt < nk; ++kt) {
#pragma unroll
        for (int i = 0; i < 4; ++i) {
            int row = i * 32 + w * 8 + lrow;
            gll16(A + (size_t)row * K + kt * 64 + k8g * 8, &a_lds[(i * 256 + w * 64) * 8]);
        }
#pragma unroll
        for (int i = 0; i < 4; ++i) {
            int row = i * 32 + w * 8 + lrow;
            gll16(Bp + (size_t)row * K + kt * 64 + k8g * 8, &b_lds[(i * 256 + w * 64) * 8]);
        }
        __syncthreads();
#pragma unroll
        for (int kk = 0; kk < 2; ++kk) {
            bf16x8 af[4], bff[4];
#pragma unroll
            for (int mt = 0; mt < 4; ++mt) {
                int row = wm * 64 + mt * 16 + l16;
                int gs = (kk * 4 + lg) ^ (row & 7);
                af[mt] = *reinterpret_cast<const bf16x8*>(a_lds + row * 64 + gs * 8);
            }
#pragma unroll
            for (int nt = 0; nt < 4; ++nt) {
                int row = wn * 64 + nt * 16 + l16;
                int gs = (kk * 4 + lg) ^ (row & 7);
                bff[nt] = *reinterpret_cast<const bf16x8*>(b_lds + row * 64 + gs * 8);
            }
#pragma unroll
            for (int mt = 0; mt < 4; ++mt)
#pragma unroll
                for (int nt = 0; nt < 4; ++nt)
                    acc[mt][nt] = mfma16(af[mt], bff[nt], acc[mt][nt]);
        }
        __syncthreads();
    }
}

// ---------------- 96x128xK variant (M-tile 96 keeps tiles inside one b: 576 = 6*96) ----------------
__device__ __forceinline__ void gemm_loop96(const unsigned short* __restrict__ A,
                                            const unsigned short* __restrict__ Bp,
                                            int K, unsigned short* a_lds, unsigned short* b_lds,
                                            int tid, f32x4 acc[3][4]) {
    const int l = tid & 63, w = tid >> 6;
    const int l16 = l & 15, lg = l >> 4;
    const int wm = w & 1, wn = w >> 1;
    const f32x4 fz = {0.f, 0.f, 0.f, 0.f};
#pragma unroll
    for (int mt = 0; mt < 3; ++mt)
#pragma unroll
        for (int nt = 0; nt < 4; ++nt) acc[mt][nt] = fz;
    const int lrow = l >> 3;
    const int k8g = (l & 7) ^ lrow;
    const int nk = K >> 6;
    for (int kt = 0; kt < nk; ++kt) {
#pragma unroll
        for (int i = 0; i < 3; ++i) {
            int row = i * 32 + w * 8 + lrow;
            gll16(A + (size_t)row * K + kt * 64 + k8g * 8, &a_lds[(i * 256 + w * 64) * 8]);
        }
#pragma unroll
        for (int i = 0; i < 4; ++i) {
            int row = i * 32 + w * 8 + lrow;
            gll16(Bp + (size_t)row * K + kt * 64 + k8g * 8, &b_lds[(i * 256 + w * 64) * 8]);
        }
        __syncthreads();
#pragma unroll
        for (int kk = 0; kk < 2; ++kk) {
            bf16x8 af[3], bff[4];
#pragma unroll
            for (int mt = 0; mt < 3; ++mt) {
                int row = wm * 48 + mt * 16 + l16;
                int gs = (kk * 4 + lg) ^ (row & 7);
                af[mt] = *reinterpret_cast<const bf16x8*>(a_lds + row * 64 + gs * 8);
            }
#pragma unroll
            for (int nt = 0; nt < 4; ++nt) {
                int row = wn * 64 + nt * 16 + l16;
                int gs = (kk * 4 + lg) ^ (row & 7);
                bff[nt] = *reinterpret_cast<const bf16x8*>(b_lds + row * 64 + gs * 8);
            }
#pragma unroll
            for (int mt = 0; mt < 3; ++mt)
#pragma unroll
                for (int nt = 0; nt < 4; ++nt)
                    acc[mt][nt] = mfma16(af[mt], bff[nt], acc[mt][nt]);
        }
        __syncthreads();
    }
}

// q GEMM:  q[br] = (xn @ (diag(g)Wq[br])^T + bias) * SCALE  -> bf16 (36864x512)
__global__ __launch_bounds__(256, 4) void k_qgemm(const unsigned short* __restrict__ xn,
                                                  const unsigned short* __restrict__ wqt,
                                                  const float* __restrict__ qbias,
                                                  unsigned short* __restrict__ qb) {
    int bid = blockIdx.x;                        // 2304 = 4bn x 288bm x 2br
    int vb = (bid & 7) * 288 + (bid >> 3);       // XCD-contiguous
    int bn = vb & 3;
    int t = vb >> 2;
    int br = (t >= 288) ? 1 : 0;
    int bm = t - br * 288;
    const unsigned short* A = xn + (size_t)bm * 128 * DIM_;
    const unsigned short* Bp = wqt + (size_t)br * 512 * 1024 + (size_t)bn * 128 * 1024;
    unsigned short* C = qb + (size_t)br * BT_ * TXT_;
    const float* bias = qbias + br * 512;
    __shared__ unsigned short a_lds[128 * 64];
    __shared__ unsigned short b_lds[128 * 64];
    f32x4 acc[4][4];
    gemm_loop_gll(A, Bp, DIM_, a_lds, b_lds, threadIdx.x, acc);
    const int l = threadIdx.x & 63, w = threadIdx.x >> 6;
    const int l16 = l & 15, lg = l >> 4, wm = w & 1, wn = w >> 1;
#pragma unroll
    for (int mt = 0; mt < 4; ++mt)
#pragma unroll
        for (int nt = 0; nt < 4; ++nt) {
            int col = bn * 128 + wn * 64 + nt * 16 + l16;
            float bv = bias[col];
#pragma unroll
            for (int r = 0; r < 4; ++r) {
                int row = bm * 128 + wm * 64 + mt * 16 + lg * 4 + r;
                C[(size_t)row * TXT_ + col] = f2bf((acc[mt][nt][r] + bv) * SCALE_);
            }
        }
}

// score GEMM: P = exp(q @ kvn^T) per branch, + row-sum atomics into denom
__global__ __launch_bounds__(256, 4) void k_score(const unsigned short* __restrict__ qbuf,
                                                  const unsigned short* __restrict__ kvn,
                                                  unsigned short* __restrict__ P,
                                                  float* __restrict__ denom, int br) {
    int bid = blockIdx.x;                        // 3072 = 64b x 6mt x 8nt
    int vb = (bid & 7) * 384 + (bid >> 3);       // XCD-contiguous, 8 b's per XCD
    int tile = vb % 48, b = vb / 48;
    int mt = tile >> 3, nt = tile & 7;
    const unsigned short* A = qbuf + ((size_t)br * BT_ + (size_t)b * TOK_ + mt * 96) * TXT_;
    const unsigned short* Bp = kvn + (size_t)b * NTQ_ * TXT_ + (size_t)nt * 128 * TXT_;
    __shared__ unsigned short a_lds[96 * 64];
    __shared__ unsigned short b_lds[128 * 64];
    f32x4 acc[3][4];
    gemm_loop96(A, Bp, TXT_, a_lds, b_lds, threadIdx.x, acc);
    const int l = threadIdx.x & 63, w = threadIdx.x >> 6;
    const int l16 = l & 15, lg = l >> 4, wm = w & 1, wn = w >> 1;
    float* dn = denom + (size_t)br * BT_;
#pragma unroll
    for (int mt2 = 0; mt2 < 3; ++mt2)
#pragma unroll
        for (int r = 0; r < 4; ++r) {
            int row = b * TOK_ + mt * 96 + wm * 48 + mt2 * 16 + lg * 4 + r;
            float s = 0.f;
#pragma unroll
            for (int nt2 = 0; nt2 < 4; ++nt2) {
                int col = nt * 128 + wn * 64 + nt2 * 16 + l16;
                float p = (col < NT_) ? __expf(acc[mt2][nt2][r]) : 0.f;
                s += p;
                P[(size_t)row * NTP_ + col] = f2bf(p);
            }
#pragma unroll
            for (int d = 1; d < 16; d <<= 1) s += __shfl_xor(s, d);
            if (l16 == 0) atomicAdd(&dn[row], s);
        }
}

// PV GEMM: O = (P @ kvt^T) / denom -> bf16; fused per-row sum (br0) / max (br1) atomics
__global__ __launch_bounds__(256, 4) void k_pv(const unsigned short* __restrict__ P,
                                               const unsigned short* __restrict__ kvt,
                                               const float* __restrict__ denom,
                                               unsigned short* __restrict__ ob,
                                               float* __restrict__ avgs,
                                               unsigned* __restrict__ maxe, int br) {
    int bid = blockIdx.x;                        // 1536 = 64b x 6mt x 4nt
    int vb = (bid & 7) * 192 + (bid >> 3);       // XCD-contiguous, 8 b's per XCD
    int tile = vb % 24, b = vb / 24;
    int mt = tile >> 2, nt = tile & 3;
    const unsigned short* A = P + ((size_t)b * TOK_ + mt * 96) * NTP_;
    const unsigned short* Bp = kvt + (size_t)b * TXT_ * NTP_ + (size_t)nt * 128 * NTP_;
    __shared__ unsigned short a_lds[96 * 64];
    __shared__ unsigned short b_lds[128 * 64];
    f32x4 acc[3][4];
    gemm_loop96(A, Bp, NTP_, a_lds, b_lds, threadIdx.x, acc);
    const int l = threadIdx.x & 63, w = threadIdx.x >> 6;
    const int l16 = l & 15, lg = l >> 4, wm = w & 1, wn = w >> 1;
    const float* dn = denom + (size_t)br * BT_;
#pragma unroll
    for (int mt2 = 0; mt2 < 3; ++mt2)
#pragma unroll
        for (int r = 0; r < 4; ++r) {
            int row = b * TOK_ + mt * 96 + wm * 48 + mt2 * 16 + lg * 4 + r;
            float inv = 1.f / dn[row];
            unsigned short* dst = ob + ((size_t)br * BT_ + row) * TXT_;
            float sum = 0.f, mx = -1e30f;
#pragma unroll
            for (int nt2 = 0; nt2 < 4; ++nt2) {
                int col = nt * 128 + wn * 64 + nt2 * 16 + l16;
                float o = acc[mt2][nt2][r] * inv;
                dst[col] = f2bf(o);
                sum += o;
                mx = fmaxf(mx, o);
            }
#pragma unroll
            for (int d = 1; d < 16; d <<= 1) {
                sum += __shfl_xor(sum, d);
                mx = fmaxf(mx, __shfl_xor(mx, d));
            }
            if (l16 == 0) {
                if (br == 0) atomicAdd(&avgs[row], sum);
                else         atomicMax(&maxe[row], encmax(mx));
            }
        }
}

// final GEMM fused with x_se: A = o1*g1 + o2*g2 computed in-register during staging.
// y = xse (36864x512) @ Wf^T (1024x512) -> fp32 scattered into out layout
__global__ __launch_bounds__(256, 4) void k_fgemm2(const unsigned short* __restrict__ o1,
                                                   const unsigned short* __restrict__ o2,
                                                   const float* __restrict__ avgs,
                                                   const unsigned* __restrict__ maxe,
                                                   const float* __restrict__ cdw,
                                                   const unsigned short* __restrict__ wfb,
                                                   float* __restrict__ out) {
    int bid = blockIdx.x;                        // 2304 = 8bn x 288bm
    int vb = (bid & 7) * 288 + (bid >> 3);
    int bn = vb & 7, bm = vb >> 3;
    const unsigned short* Bp = wfb + (size_t)bn * 128 * TXT_;
    __shared__ unsigned short a_lds[128 * 64];
    __shared__ unsigned short b_lds[128 * 64];
    __shared__ float glds[128][2];
    const int tid = threadIdx.x;
    // ---- prologue: per-row gates (3x3 conv on avg/max stats + sigmoid)
    if (tid < 128) {
        int rowg = bm * 128 + tid;
        int b = rowg / TOK_, hw = rowg - b * TOK_, h = hw / H_, ww = hw - h * H_;
        float a1 = 0.f, a2 = 0.f;
#pragma unroll
        for (int ky = 0; ky < 3; ++ky)
#pragma unroll
            for (int kx = 0; kx < 3; ++kx) {
                int hh = h + ky - 1, wx = ww + kx - 1;
                if (hh >= 0 && hh < H_ && wx >= 0 && wx < H_) {
                    float wv = cdw[ky * 3 + kx];
                    int s = b * TOK_ + hh * H_ + wx;
                    a1 += wv * avgs[s] * (1.f / TXT_);
                    a2 += wv * decmax(maxe[s]);
                }
            }
        glds[tid][0] = 1.f / (1.f + __expf(-a1));
        glds[tid][1] = 1.f / (1.f + __expf(-a2));
    }
    __syncthreads();
    // ---- main loop (m97 structure; A reg-staged with gate combine, B via global_load_lds)
    const int l = tid & 63, w = tid >> 6;
    const int l16 = l & 15, lg = l >> 4;
    const int wm = w & 1, wn = w >> 1;
    const f32x4 fz = {0.f, 0.f, 0.f, 0.f};
    f32x4 acc[4][4];
#pragma unroll
    for (int mt = 0; mt < 4; ++mt)
#pragma unroll
        for (int nt = 0; nt < 4; ++nt) acc[mt][nt] = fz;
    const int lrow = l >> 3;
    const int k8g = (l & 7) ^ lrow;        // pre-swizzled source granule (B path)
    const int gA = l & 7;                  // unswizzled source granule (A path)
    for (int kt = 0; kt < 8; ++kt) {       // K = 512
#pragma unroll
        for (int i = 0; i < 4; ++i) {
            int row = i * 32 + w * 8 + lrow;
            size_t goff = (size_t)(bm * 128 + row) * TXT_ + kt * 64 + gA * 8;
            uint4 va = *reinterpret_cast<const uint4*>(o1 + goff);
            uint4 vb2 = *reinterpret_cast<const uint4*>(o2 + goff);
            float f1[8], f2[8];
            unpack8(va, f1); unpack8(vb2, f2);
            float gg1 = glds[row][0], gg2 = glds[row][1];
            unsigned rr[4];
#pragma unroll
            for (int j = 0; j < 4; ++j) {
                unsigned lo = f2bf(f1[2 * j] * gg1 + f2[2 * j] * gg2);
                unsigned hi = f2bf(f1[2 * j + 1] * gg1 + f2[2 * j + 1] * gg2);
                rr[j] = lo | (hi << 16);
            }
            *reinterpret_cast<uint4*>(a_lds + row * 64 + (gA ^ (row & 7)) * 8) = make_uint4(rr[0], rr[1], rr[2], rr[3]);
        }
#pragma unroll
        for (int i = 0; i < 4; ++i) {
            int row = i * 32 + w * 8 + lrow;
            gll16(Bp + (size_t)row * TXT_ + kt * 64 + k8g * 8, &b_lds[(i * 256 + w * 64) * 8]);
        }
        __syncthreads();
#pragma unroll
        for (int kk = 0; kk < 2; ++kk) {
            bf16x8 af[4], bff[4];
#pragma unroll
            for (int mt = 0; mt < 4; ++mt) {
                int row = wm * 64 + mt * 16 + l16;
                int gs = (kk * 4 + lg) ^ (row & 7);
                af[mt] = *reinterpret_cast<const bf16x8*>(a_lds + row * 64 + gs * 8);
            }
#pragma unroll
            for (int nt = 0; nt < 4; ++nt) {
                int row = wn * 64 + nt * 16 + l16;
                int gs = (kk * 4 + lg) ^ (row & 7);
                bff[nt] = *reinterpret_cast<const bf16x8*>(b_lds + row * 64 + gs * 8);
            }
#pragma unroll
            for (int mt = 0; mt < 4; ++mt)
#pragma unroll
                for (int nt = 0; nt < 4; ++nt)
                    acc[mt][nt] = mfma16(af[mt], bff[nt], acc[mt][nt]);
        }
        __syncthreads();
    }
    // ---- epilogue
#pragma unroll
    for (int mt = 0; mt < 4; ++mt)
#pragma unroll
        for (int r = 0; r < 4; ++r) {
            int rowg = bm * 128 + wm * 64 + mt * 16 + lg * 4 + r;
            int b = rowg / TOK_, tk = rowg - b * TOK_;
            float* dst = out + ((size_t)(tk + 1) * B_ + b) * DIM_;
#pragma unroll
            for (int nt = 0; nt < 4; ++nt) {
                int col = bn * 128 + wn * 64 + nt * 16 + l16;
                dst[col] = acc[mt][nt][r];
            }
        }
}

// ---------------- launcher ----------------
extern "C" void kernel_launch(void* const* d_in, const int* in_sizes, int n_in,
                              void* d_out, int out_size, void* d_ws, size_t ws_size,
                              hipStream_t stream) {
    (void)in_sizes; (void)n_in; (void)out_size; (void)ws_size;
    const float* x    = (const float*)d_in[0];
    const float* tf   = (const float*)d_in[1];
    const float* lq1g = (const float*)d_in[2];
    const float* lq1b = (const float*)d_in[3];
    const float* lq2g = (const float*)d_in[4];
    const float* lq2b = (const float*)d_in[5];
    const float* lkvg = (const float*)d_in[6];
    const float* lkvb = (const float*)d_in[7];
    const float* wq1  = (const float*)d_in[8];
    const float* wq2  = (const float*)d_in[9];
    const float* cdw  = (const float*)d_in[10];
    const float* wf   = (const float*)d_in[11];
    float* out = (float*)d_out;

    char* ws = (char*)d_ws;
    size_t off = 0;
    auto carve = [&](size_t bytes) { char* p = ws + off; off += (bytes + 255) & ~(size_t)255; return p; };
    unsigned short* kvn  = (unsigned short*)carve((size_t)B_ * NTQ_ * TXT_ * 2);       // 67.1 MB
    unsigned short* kvt  = (unsigned short*)carve((size_t)B_ * TXT_ * NTP_ * 2);       // 67.1 MB
    unsigned short* wqt  = (unsigned short*)carve((size_t)2 * 512 * 1024 * 2);         // 2 MB
    unsigned short* wfb  = (unsigned short*)carve((size_t)1024 * 512 * 2);             // 1 MB
    float* qbias = (float*)carve((size_t)2 * 512 * 4);
    float* stats = (float*)carve((size_t)4 * BT_ * 4);                                 // denom[2BT] | avgs[BT] | maxe[BT]
    float* denom = stats;
    float* avgs  = stats + 2 * BT_;
    unsigned* maxe = (unsigned*)(stats + 3 * BT_);
    unsigned short* xn   = (unsigned short*)carve((size_t)BT_ * DIM_ * 2);             // 75.5 MB
    unsigned short* qbuf = (unsigned short*)carve((size_t)2 * BT_ * TXT_ * 2);         // 75.5 MB
    unsigned short* ob   = (unsigned short*)carve((size_t)2 * BT_ * TXT_ * 2);         // 75.5 MB
    unsigned short* Pm   = xn;     // P (36864x1024 bf16, per branch): xn dead after k_qgemm

    // row 0 of output = x_cls
    hipMemcpyAsync(out, x, (size_t)B_ * DIM_ * sizeof(float), hipMemcpyDeviceToDevice, stream);

    k_prep_wq<<<256, 256, 0, stream>>>(wq1, wq2, lq1g, lq2g, wqt);
    k_qbias<<<16, 256, 0, stream>>>(wq1, wq2, lq1b, lq2b, qbias);
    k_f2bf<<<512, 256, 0, stream>>>(wf, wfb, 131072);
    k_kvln<<<8192, 512, 0, stream>>>(tf, lkvg, lkvb, kvn);
    k_kvt<<<8192, 256, 0, stream>>>(kvn, kvt);
    k_xln<<<4608, 512, 0, stream>>>(x, xn);
    k_qgemm<<<2304, 256, 0, stream>>>(xn, wqt, qbias, qbuf);
    hipMemsetAsync(stats, 0, (size_t)4 * BT_ * 4, stream);
    // branch 0
    k_score<<<3072, 256, 0, stream>>>(qbuf, kvn, Pm, denom, 0);
    k_pv<<<1536, 256, 0, stream>>>(Pm, kvt, denom, ob, avgs, maxe, 0);
    // branch 1 (P buffer reused; stream-ordered)
    k_score<<<3072, 256, 0, stream>>>(qbuf, kvn, Pm, denom, 1);
    k_pv<<<1536, 256, 0, stream>>>(Pm, kvt, denom, ob, avgs, maxe, 1);
    k_fgemm2<<<2304, 256, 0, stream>>>(ob, ob + (size_t)BT_ * TXT_, avgs, maxe, cdw, wfb, out);
}

// Round 7
// 624.436 us; speedup vs baseline: 1.2687x; 1.0174x over previous
//
#include <hip/hip_runtime.h>

// ---------------- problem constants ----------------
#define B_    64
#define TOK_  576
#define DIM_  1024
#define TXT_  512
#define NT_   1000
#define NTQ_  1024                 // kvn padded rows (zero-filled 1000..1023)
#define NTP_  1024                 // kvt padded cols / P padded cols
#define H_    24
#define BT_   (B_ * TOK_)          // 36864 rows
static constexpr float SCALE_ = 0.0441941738241592f;   // 512^-0.5

typedef __bf16 bf16x8 __attribute__((ext_vector_type(8)));
typedef float  f32x4  __attribute__((ext_vector_type(4)));

__device__ __forceinline__ unsigned short f2bf(float f) {
    unsigned u = __float_as_uint(f);
    u += 0x7fffu + ((u >> 16) & 1u);
    return (unsigned short)(u >> 16);
}
__device__ __forceinline__ float bf2f(unsigned short h) {
    return __uint_as_float(((unsigned)h) << 16);
}
__device__ __forceinline__ f32x4 mfma16(bf16x8 a, bf16x8 b, f32x4 c) {
    return __builtin_amdgcn_mfma_f32_16x16x32_bf16(a, b, c, 0, 0, 0);
}
__device__ __forceinline__ void unpack8(uint4 v, float* f) {
    unsigned a0 = v.x, a1 = v.y, a2 = v.z, a3 = v.w;
    f[0] = bf2f((unsigned short)(a0 & 0xffff)); f[1] = bf2f((unsigned short)(a0 >> 16));
    f[2] = bf2f((unsigned short)(a1 & 0xffff)); f[3] = bf2f((unsigned short)(a1 >> 16));
    f[4] = bf2f((unsigned short)(a2 & 0xffff)); f[5] = bf2f((unsigned short)(a2 >> 16));
    f[6] = bf2f((unsigned short)(a3 & 0xffff)); f[7] = bf2f((unsigned short)(a3 >> 16));
}
// order-preserving float->uint encoding for atomicMax over signed floats
__device__ __forceinline__ unsigned encmax(float f) {
    unsigned u = __float_as_uint(f);
    return (u & 0x80000000u) ? ~u : (u | 0x80000000u);
}
__device__ __forceinline__ float decmax(unsigned k) {
    unsigned u = (k & 0x80000000u) ? (k ^ 0x80000000u) : ~k;
    return __uint_as_float(u);
}

// async global->LDS, 16B per lane; lds base wave-uniform, lanes land at base + lane*16
typedef const __attribute__((address_space(1))) unsigned int* as1_u32p;
typedef __attribute__((address_space(3))) unsigned int* as3_u32p;
__device__ __forceinline__ void gll16(const void* g, void* l) {
    __builtin_amdgcn_global_load_lds((as1_u32p)g, (as3_u32p)l, 16, 0, 0);
}

// ---------------- merged weight prep: [0,256) prep_wq | [256,272) qbias | [272,784) f2bf ----------------
__global__ void k_prep(const float* __restrict__ wq1, const float* __restrict__ wq2,
                       const float* __restrict__ g1, const float* __restrict__ g2,
                       const float* __restrict__ b1, const float* __restrict__ b2,
                       const float* __restrict__ wf,
                       unsigned short* __restrict__ wqt, float* __restrict__ qbias,
                       unsigned short* __restrict__ wfb) {
    __shared__ float tile[64][68];
    int bx = blockIdx.x, t = threadIdx.x;
    if (bx < 256) {
        // Wq (1024x512 f32), rows pre-scaled by LN gamma -> WqT bf16 [branch][512][1024]
        int br = bx >> 7, kt = (bx >> 3) & 15, nt = bx & 7;
        const float* wq = br ? wq2 : wq1;
        const float* gg = br ? g2 : g1;
#pragma unroll
        for (int i = 0; i < 4; ++i) {
            int idx4 = t + i * 256;
            int kl = idx4 >> 4, n4 = (idx4 & 15) * 4;
            float gv = gg[kt * 64 + kl];
            float4 v = *reinterpret_cast<const float4*>(wq + (size_t)(kt * 64 + kl) * 512 + nt * 64 + n4);
            tile[kl][n4 + 0] = v.x * gv; tile[kl][n4 + 1] = v.y * gv;
            tile[kl][n4 + 2] = v.z * gv; tile[kl][n4 + 3] = v.w * gv;
        }
        __syncthreads();
#pragma unroll
        for (int i = 0; i < 4; ++i) {
            int idx4 = t + i * 256;
            int nl = idx4 >> 4, k4 = (idx4 & 15) * 4;
            ushort4 o = make_ushort4(f2bf(tile[k4 + 0][nl]), f2bf(tile[k4 + 1][nl]),
                                     f2bf(tile[k4 + 2][nl]), f2bf(tile[k4 + 3][nl]));
            *reinterpret_cast<ushort4*>(wqt + (size_t)br * 512 * 1024 + (size_t)(nt * 64 + nl) * 1024 + kt * 64 + k4) = o;
        }
    } else if (bx < 272) {
        // qbias[br][e] = sum_d beta[d] * Wq[d][e]
        int bb2 = bx - 256;
        int br = bb2 >> 3, e0 = (bb2 & 7) * 64;
        int e = e0 + (t & 63), part = t >> 6;
        const float* wq = br ? wq2 : wq1;
        const float* bb = br ? b2 : b1;
        float s = 0.f;
        for (int d = part * 256; d < part * 256 + 256; ++d) s += bb[d] * wq[(size_t)d * 512 + e];
        float* red = &tile[0][0];
        red[t] = s;
        __syncthreads();
        if (t < 64) qbias[br * 512 + e0 + t] = red[t] + red[64 + t] + red[128 + t] + red[192 + t];
    } else {
        // Wf f32 -> bf16 (131072 float4 groups over 512 blocks)
        int i = (bx - 272) * 256 + t;
        float4 v = *reinterpret_cast<const float4*>(wf + (size_t)i * 4);
        ushort4 o = make_ushort4(f2bf(v.x), f2bf(v.y), f2bf(v.z), f2bf(v.w));
        *reinterpret_cast<ushort4*>(wfb + (size_t)i * 4) = o;
    }
}

// ---------------- merged layernorms, wave-per-row ----------------
// [0,8192): kv rows -> kvn bf16 [b][n_pad1024][e];  [8192,12800): x rows -> xn (normalized only)
__global__ __launch_bounds__(512, 2) void k_lnorm(const float* __restrict__ tf,
                                                  const float* __restrict__ g,
                                                  const float* __restrict__ bta,
                                                  const float* __restrict__ x,
                                                  unsigned short* __restrict__ kvn,
                                                  unsigned short* __restrict__ xn) {
    int bid = blockIdx.x;
    int l = threadIdx.x & 63;
    if (bid < 8192) {
        int row = bid * 8 + (threadIdx.x >> 6);      // b*1024 + n
        int b = row >> 10, n = row & 1023;
        unsigned short* dst = kvn + ((size_t)b * NTQ_ + n) * TXT_ + l * 8;
        if (n >= NT_) {                              // zero-pad rows
            *reinterpret_cast<uint4*>(dst) = make_uint4(0, 0, 0, 0);
            return;
        }
        const float* src = tf + ((size_t)n * B_ + b) * TXT_ + l * 8;
        float4 v0 = *reinterpret_cast<const float4*>(src);
        float4 v1 = *reinterpret_cast<const float4*>(src + 4);
        float s  = v0.x + v0.y + v0.z + v0.w + v1.x + v1.y + v1.z + v1.w;
        float ss = v0.x * v0.x + v0.y * v0.y + v0.z * v0.z + v0.w * v0.w
                 + v1.x * v1.x + v1.y * v1.y + v1.z * v1.z + v1.w * v1.w;
#pragma unroll
        for (int d = 1; d < 64; d <<= 1) { s += __shfl_xor(s, d); ss += __shfl_xor(ss, d); }
        float m = s * (1.f / TXT_);
        float rs = rsqrtf(ss * (1.f / TXT_) - m * m + 1e-5f);
        float4 g0 = *reinterpret_cast<const float4*>(g + l * 8);
        float4 g1 = *reinterpret_cast<const float4*>(g + l * 8 + 4);
        float4 b0 = *reinterpret_cast<const float4*>(bta + l * 8);
        float4 b1 = *reinterpret_cast<const float4*>(bta + l * 8 + 4);
        unsigned r0 = (unsigned)f2bf((v0.x - m) * rs * g0.x + b0.x) | ((unsigned)f2bf((v0.y - m) * rs * g0.y + b0.y) << 16);
        unsigned r1 = (unsigned)f2bf((v0.z - m) * rs * g0.z + b0.z) | ((unsigned)f2bf((v0.w - m) * rs * g0.w + b0.w) << 16);
        unsigned r2 = (unsigned)f2bf((v1.x - m) * rs * g1.x + b1.x) | ((unsigned)f2bf((v1.y - m) * rs * g1.y + b1.y) << 16);
        unsigned r3 = (unsigned)f2bf((v1.z - m) * rs * g1.z + b1.z) | ((unsigned)f2bf((v1.w - m) * rs * g1.w + b1.w) << 16);
        *reinterpret_cast<uint4*>(dst) = make_uint4(r0, r1, r2, r3);
    } else {
        int bt = (bid - 8192) * 8 + (threadIdx.x >> 6);  // b*TOK + t
        int b = bt / TOK_, tk = bt - b * TOK_;
        const float* src = x + ((size_t)(tk + 1) * B_ + b) * DIM_ + l * 16;
        float4 v[4];
#pragma unroll
        for (int j = 0; j < 4; ++j) v[j] = *reinterpret_cast<const float4*>(src + j * 4);
        float s = 0.f, ss = 0.f;
#pragma unroll
        for (int j = 0; j < 4; ++j) {
            s += v[j].x + v[j].y + v[j].z + v[j].w;
            ss += v[j].x * v[j].x + v[j].y * v[j].y + v[j].z * v[j].z + v[j].w * v[j].w;
        }
#pragma unroll
        for (int d = 1; d < 64; d <<= 1) { s += __shfl_xor(s, d); ss += __shfl_xor(ss, d); }
        float m = s * (1.f / DIM_);
        float rs = rsqrtf(ss * (1.f / DIM_) - m * m + 1e-5f);
        unsigned short* dst = xn + (size_t)bt * DIM_ + l * 16;
#pragma unroll
        for (int h = 0; h < 2; ++h) {
            unsigned r0 = (unsigned)f2bf((v[2*h].x - m) * rs) | ((unsigned)f2bf((v[2*h].y - m) * rs) << 16);
            unsigned r1 = (unsigned)f2bf((v[2*h].z - m) * rs) | ((unsigned)f2bf((v[2*h].w - m) * rs) << 16);
            unsigned r2 = (unsigned)f2bf((v[2*h+1].x - m) * rs) | ((unsigned)f2bf((v[2*h+1].y - m) * rs) << 16);
            unsigned r3 = (unsigned)f2bf((v[2*h+1].z - m) * rs) | ((unsigned)f2bf((v[2*h+1].w - m) * rs) << 16);
            *reinterpret_cast<uint4*>(dst + h * 8) = make_uint4(r0, r1, r2, r3);
        }
    }
}

// ---------------- kv transpose:  kvn [b][n][e] -> kvt [b][e][n_pad1024] ----------------
__global__ void k_kvt(const unsigned short* __restrict__ kvn, unsigned short* __restrict__ kvt) {
    __shared__ unsigned short tile[64][68];
    int bx = blockIdx.x;
    int b = bx >> 7, rem = bx & 127, et = rem >> 4, nt = rem & 15;
    int t = threadIdx.x;
#pragma unroll
    for (int i = 0; i < 4; ++i) {
        int idx4 = t + i * 256;
        int nl = idx4 >> 4, e4 = (idx4 & 15) * 4;
        int ng = nt * 64 + nl;
        ushort4 v = make_ushort4(0, 0, 0, 0);
        if (ng < NT_) v = *reinterpret_cast<const ushort4*>(kvn + ((size_t)b * NTQ_ + ng) * TXT_ + et * 64 + e4);
        tile[nl][e4 + 0] = v.x; tile[nl][e4 + 1] = v.y; tile[nl][e4 + 2] = v.z; tile[nl][e4 + 3] = v.w;
    }
    __syncthreads();
#pragma unroll
    for (int i = 0; i < 4; ++i) {
        int idx4 = t + i * 256;
        int el = idx4 >> 4, n4 = (idx4 & 15) * 4;
        ushort4 o = make_ushort4(tile[n4 + 0][el], tile[n4 + 1][el], tile[n4 + 2][el], tile[n4 + 3][el]);
        *reinterpret_cast<ushort4*>(kvt + ((size_t)b * TXT_ + et * 64 + el) * NTP_ + nt * 64 + n4) = o;
    }
}

// ---------------- 128x128xK bf16 GEMM mainloop, global_load_lds staging (m97 structure) ----------------
// A:[M][K], B:[N][K], both k-contiguous.
__device__ __forceinline__ void gemm_loop_gll(const unsigned short* __restrict__ A,
                                              const unsigned short* __restrict__ Bp,
                                              int K, unsigned short* a_lds, unsigned short* b_lds,
                                              int tid, f32x4 acc[4][4]) {
    const int l = tid & 63, w = tid >> 6;
    const int l16 = l & 15, lg = l >> 4;
    const int wm = w & 1, wn = w >> 1;
    const f32x4 fz = {0.f, 0.f, 0.f, 0.f};
#pragma unroll
    for (int mt = 0; mt < 4; ++mt)
#pragma unroll
        for (int nt = 0; nt < 4; ++nt) acc[mt][nt] = fz;
    const int lrow = l >> 3;               // 0..7
    const int k8g = (l & 7) ^ lrow;        // pre-swizzled source granule
    const int nk = K >> 6;
    for (int kt = 0; kt < nk; ++kt) {
#pragma unroll
        for (int i = 0; i < 4; ++i) {
            int row = i * 32 + w * 8 + lrow;
            gll16(A + (size_t)row * K + kt * 64 + k8g * 8, &a_lds[(i * 256 + w * 64) * 8]);
        }
#pragma unroll
        for (int i = 0; i < 4; ++i) {
            int row = i * 32 + w * 8 + lrow;
            gll16(Bp + (size_t)row * K + kt * 64 + k8g * 8, &b_lds[(i * 256 + w * 64) * 8]);
        }
        __syncthreads();
#pragma unroll
        for (int kk = 0; kk < 2; ++kk) {
            bf16x8 af[4], bff[4];
#pragma unroll
            for (int mt = 0; mt < 4; ++mt) {
                int row = wm * 64 + mt * 16 + l16;
                int gs = (kk * 4 + lg) ^ (row & 7);
                af[mt] = *reinterpret_cast<const bf16x8*>(a_lds + row * 64 + gs * 8);
            }
#pragma unroll
            for (int nt = 0; nt < 4; ++nt) {
                int row = wn * 64 + nt * 16 + l16;
                int gs = (kk * 4 + lg) ^ (row & 7);
                bff[nt] = *reinterpret_cast<const bf16x8*>(b_lds + row * 64 + gs * 8);
            }
#pragma unroll
            for (int mt = 0; mt < 4; ++mt)
#pragma unroll
                for (int nt = 0; nt < 4; ++nt)
                    acc[mt][nt] = mfma16(af[mt], bff[nt], acc[mt][nt]);
        }
        __syncthreads();
    }
}

// ---------------- 96x128xK variant (M-tile 96 keeps tiles inside one b: 576 = 6*96) ----------------
__device__ __forceinline__ void gemm_loop96(const unsigned short* __restrict__ A,
                                            const unsigned short* __restrict__ Bp,
                                            int K, unsigned short* a_lds, unsigned short* b_lds,
                                            int tid, f32x4 acc[3][4]) {
    const int l = tid & 63, w = tid >> 6;
    const int l16 = l & 15, lg = l >> 4;
    const int wm = w & 1, wn = w >> 1;
    const f32x4 fz = {0.f, 0.f, 0.f, 0.f};
#pragma unroll
    for (int mt = 0; mt < 3; ++mt)
#pragma unroll
        for (int nt = 0; nt < 4; ++nt) acc[mt][nt] = fz;
    const int lrow = l >> 3;
    const int k8g = (l & 7) ^ lrow;
    const int nk = K >> 6;
    for (int kt = 0; kt < nk; ++kt) {
#pragma unroll
        for (int i = 0; i < 3; ++i) {
            int row = i * 32 + w * 8 + lrow;
            gll16(A + (size_t)row * K + kt * 64 + k8g * 8, &a_lds[(i * 256 + w * 64) * 8]);
        }
#pragma unroll
        for (int i = 0; i < 4; ++i) {
            int row = i * 32 + w * 8 + lrow;
            gll16(Bp + (size_t)row * K + kt * 64 + k8g * 8, &b_lds[(i * 256 + w * 64) * 8]);
        }
        __syncthreads();
#pragma unroll
        for (int kk = 0; kk < 2; ++kk) {
            bf16x8 af[3], bff[4];
#pragma unroll
            for (int mt = 0; mt < 3; ++mt) {
                int row = wm * 48 + mt * 16 + l16;
                int gs = (kk * 4 + lg) ^ (row & 7);
                af[mt] = *reinterpret_cast<const bf16x8*>(a_lds + row * 64 + gs * 8);
            }
#pragma unroll
            for (int nt = 0; nt < 4; ++nt) {
                int row = wn * 64 + nt * 16 + l16;
                int gs = (kk * 4 + lg) ^ (row & 7);
                bff[nt] = *reinterpret_cast<const bf16x8*>(b_lds + row * 64 + gs * 8);
            }
#pragma unroll
            for (int mt = 0; mt < 3; ++mt)
#pragma unroll
                for (int nt = 0; nt < 4; ++nt)
                    acc[mt][nt] = mfma16(af[mt], bff[nt], acc[mt][nt]);
        }
        __syncthreads();
    }
}

// q GEMM:  q[br] = (xn @ (diag(g)Wq[br])^T + bias) * SCALE  -> bf16 (36864x512)
__global__ __launch_bounds__(256, 4) void k_qgemm(const unsigned short* __restrict__ xn,
                                                  const unsigned short* __restrict__ wqt,
                                                  const float* __restrict__ qbias,
                                                  unsigned short* __restrict__ qb) {
    int bid = blockIdx.x;                        // 2304 = 4bn x 288bm x 2br
    int vb = (bid & 7) * 288 + (bid >> 3);       // XCD-contiguous
    int bn = vb & 3;
    int t = vb >> 2;
    int br = (t >= 288) ? 1 : 0;
    int bm = t - br * 288;
    const unsigned short* A = xn + (size_t)bm * 128 * DIM_;
    const unsigned short* Bp = wqt + (size_t)br * 512 * 1024 + (size_t)bn * 128 * 1024;
    unsigned short* C = qb + (size_t)br * BT_ * TXT_;
    const float* bias = qbias + br * 512;
    __shared__ unsigned short a_lds[128 * 64];
    __shared__ unsigned short b_lds[128 * 64];
    f32x4 acc[4][4];
    gemm_loop_gll(A, Bp, DIM_, a_lds, b_lds, threadIdx.x, acc);
    const int l = threadIdx.x & 63, w = threadIdx.x >> 6;
    const int l16 = l & 15, lg = l >> 4, wm = w & 1, wn = w >> 1;
#pragma unroll
    for (int mt = 0; mt < 4; ++mt)
#pragma unroll
        for (int nt = 0; nt < 4; ++nt) {
            int col = bn * 128 + wn * 64 + nt * 16 + l16;
            float bv = bias[col];
#pragma unroll
            for (int r = 0; r < 4; ++r) {
                int row = bm * 128 + wm * 64 + mt * 16 + lg * 4 + r;
                C[(size_t)row * TXT_ + col] = f2bf((acc[mt][nt][r] + bv) * SCALE_);
            }
        }
}

// score GEMM: P = exp(q @ kvn^T) per branch, + row-sum atomics into denom
__global__ __launch_bounds__(256, 4) void k_score(const unsigned short* __restrict__ qbuf,
                                                  const unsigned short* __restrict__ kvn,
                                                  unsigned short* __restrict__ P,
                                                  float* __restrict__ denom, int br) {
    int bid = blockIdx.x;                        // 3072 = 64b x 6mt x 8nt
    int vb = (bid & 7) * 384 + (bid >> 3);       // XCD-contiguous, 8 b's per XCD
    int tile = vb % 48, b = vb / 48;
    int mt = tile >> 3, nt = tile & 7;
    const unsigned short* A = qbuf + ((size_t)br * BT_ + (size_t)b * TOK_ + mt * 96) * TXT_;
    const unsigned short* Bp = kvn + (size_t)b * NTQ_ * TXT_ + (size_t)nt * 128 * TXT_;
    __shared__ unsigned short a_lds[96 * 64];
    __shared__ unsigned short b_lds[128 * 64];
    f32x4 acc[3][4];
    gemm_loop96(A, Bp, TXT_, a_lds, b_lds, threadIdx.x, acc);
    const int l = threadIdx.x & 63, w = threadIdx.x >> 6;
    const int l16 = l & 15, lg = l >> 4, wm = w & 1, wn = w >> 1;
    float* dn = denom + (size_t)br * BT_;
#pragma unroll
    for (int mt2 = 0; mt2 < 3; ++mt2)
#pragma unroll
        for (int r = 0; r < 4; ++r) {
            int row = b * TOK_ + mt * 96 + wm * 48 + mt2 * 16 + lg * 4 + r;
            float s = 0.f;
#pragma unroll
            for (int nt2 = 0; nt2 < 4; ++nt2) {
                int col = nt * 128 + wn * 64 + nt2 * 16 + l16;
                float p = (col < NT_) ? __expf(acc[mt2][nt2][r]) : 0.f;
                s += p;
                P[(size_t)row * NTP_ + col] = f2bf(p);
            }
#pragma unroll
            for (int d = 1; d < 16; d <<= 1) s += __shfl_xor(s, d);
            if (l16 == 0) atomicAdd(&dn[row], s);
        }
}

// PV GEMM: O = (P @ kvt^T) / denom -> bf16; fused per-row sum (br0) / max (br1) atomics
__global__ __launch_bounds__(256, 4) void k_pv(const unsigned short* __restrict__ P,
                                               const unsigned short* __restrict__ kvt,
                                               const float* __restrict__ denom,
                                               unsigned short* __restrict__ ob,
                                               float* __restrict__ avgs,
                                               unsigned* __restrict__ maxe, int br) {
    int bid = blockIdx.x;                        // 1536 = 64b x 6mt x 4nt
    int vb = (bid & 7) * 192 + (bid >> 3);       // XCD-contiguous, 8 b's per XCD
    int tile = vb % 24, b = vb / 24;
    int mt = tile >> 2, nt = tile & 3;
    const unsigned short* A = P + ((size_t)b * TOK_ + mt * 96) * NTP_;
    const unsigned short* Bp = kvt + (size_t)b * TXT_ * NTP_ + (size_t)nt * 128 * NTP_;
    __shared__ unsigned short a_lds[96 * 64];
    __shared__ unsigned short b_lds[128 * 64];
    f32x4 acc[3][4];
    gemm_loop96(A, Bp, NTP_, a_lds, b_lds, threadIdx.x, acc);
    const int l = threadIdx.x & 63, w = threadIdx.x >> 6;
    const int l16 = l & 15, lg = l >> 4, wm = w & 1, wn = w >> 1;
    const float* dn = denom + (size_t)br * BT_;
#pragma unroll
    for (int mt2 = 0; mt2 < 3; ++mt2)
#pragma unroll
        for (int r = 0; r < 4; ++r) {
            int row = b * TOK_ + mt * 96 + wm * 48 + mt2 * 16 + lg * 4 + r;
            float inv = 1.f / dn[row];
            unsigned short* dst = ob + ((size_t)br * BT_ + row) * TXT_;
            float sum = 0.f, mx = -1e30f;
#pragma unroll
            for (int nt2 = 0; nt2 < 4; ++nt2) {
                int col = nt * 128 + wn * 64 + nt2 * 16 + l16;
                float o = acc[mt2][nt2][r] * inv;
                dst[col] = f2bf(o);
                sum += o;
                mx = fmaxf(mx, o);
            }
#pragma unroll
            for (int d = 1; d < 16; d <<= 1) {
                sum += __shfl_xor(sum, d);
                mx = fmaxf(mx, __shfl_xor(mx, d));
            }
            if (l16 == 0) {
                if (br == 0) atomicAdd(&avgs[row], sum);
                else         atomicMax(&maxe[row], encmax(mx));
            }
        }
}

// final GEMM: y = xse (36864x512) @ Wf^T (1024x512) -> fp32 scattered into out layout
__global__ __launch_bounds__(256, 4) void k_fgemm(const unsigned short* __restrict__ xse,
                                                  const unsigned short* __restrict__ wfb,
                                                  float* __restrict__ out) {
    int bid = blockIdx.x;                        // 2304 = 8bn x 288bm
    int vb = (bid & 7) * 288 + (bid >> 3);
    int bn = vb & 7, bm = vb >> 3;
    const unsigned short* A = xse + (size_t)bm * 128 * TXT_;
    const unsigned short* Bp = wfb + (size_t)bn * 128 * TXT_;
    __shared__ unsigned short a_lds[128 * 64];
    __shared__ unsigned short b_lds[128 * 64];
    f32x4 acc[4][4];
    gemm_loop_gll(A, Bp, TXT_, a_lds, b_lds, threadIdx.x, acc);
    const int l = threadIdx.x & 63, w = threadIdx.x >> 6;
    const int l16 = l & 15, lg = l >> 4, wm = w & 1, wn = w >> 1;
#pragma unroll
    for (int mt = 0; mt < 4; ++mt)
#pragma unroll
        for (int r = 0; r < 4; ++r) {
            int rowg = bm * 128 + wm * 64 + mt * 16 + lg * 4 + r;
            int b = rowg / TOK_, tk = rowg - b * TOK_;
            float* dst = out + ((size_t)(tk + 1) * B_ + b) * DIM_;
#pragma unroll
            for (int nt = 0; nt < 4; ++nt) {
                int col = bn * 128 + wn * 64 + nt * 16 + l16;
                dst[col] = acc[mt][nt][r];
            }
        }
}

// ---------------- x_se = o1*g1 + o2*g2 -> bf16, with gate conv fused (lane 0 per row) ----------------
__global__ void k_xse(const unsigned short* __restrict__ o1, const unsigned short* __restrict__ o2,
                      const float* __restrict__ avgs, const unsigned* __restrict__ maxe,
                      const float* __restrict__ cdw, unsigned short* __restrict__ xse) {
    int idx8 = blockIdx.x * 256 + threadIdx.x;    // < 36864*64
    int bt = idx8 >> 6, e8 = threadIdx.x & 63;
    float gg1 = 0.f, gg2 = 0.f;
    if (e8 == 0) {
        int b = bt / TOK_, hw = bt - b * TOK_, h = hw / H_, ww = hw - h * H_;
        float a1 = 0.f, a2 = 0.f;
#pragma unroll
        for (int ky = 0; ky < 3; ++ky)
#pragma unroll
            for (int kx = 0; kx < 3; ++kx) {
                int hh = h + ky - 1, wx = ww + kx - 1;
                if (hh >= 0 && hh < H_ && wx >= 0 && wx < H_) {
                    float wv = cdw[ky * 3 + kx];
                    int s = b * TOK_ + hh * H_ + wx;
                    a1 += wv * avgs[s] * (1.f / TXT_);
                    a2 += wv * decmax(maxe[s]);
                }
            }
        gg1 = 1.f / (1.f + __expf(-a1));
        gg2 = 1.f / (1.f + __expf(-a2));
    }
    gg1 = __shfl(gg1, 0);
    gg2 = __shfl(gg2, 0);
    float f1[8], f2[8];
    unpack8(*reinterpret_cast<const uint4*>(o1 + (size_t)bt * TXT_ + e8 * 8), f1);
    unpack8(*reinterpret_cast<const uint4*>(o2 + (size_t)bt * TXT_ + e8 * 8), f2);
    unsigned r[4];
#pragma unroll
    for (int j = 0; j < 4; ++j) {
        unsigned lo = f2bf(f1[2 * j] * gg1 + f2[2 * j] * gg2);
        unsigned hi = f2bf(f1[2 * j + 1] * gg1 + f2[2 * j + 1] * gg2);
        r[j] = lo | (hi << 16);
    }
    uint4 o = make_uint4(r[0], r[1], r[2], r[3]);
    *reinterpret_cast<uint4*>(xse + (size_t)bt * TXT_ + e8 * 8) = o;
}

// ---------------- launcher ----------------
extern "C" void kernel_launch(void* const* d_in, const int* in_sizes, int n_in,
                              void* d_out, int out_size, void* d_ws, size_t ws_size,
                              hipStream_t stream) {
    (void)in_sizes; (void)n_in; (void)out_size; (void)ws_size;
    const float* x    = (const float*)d_in[0];
    const float* tf   = (const float*)d_in[1];
    const float* lq1g = (const float*)d_in[2];
    const float* lq1b = (const float*)d_in[3];
    const float* lq2g = (const float*)d_in[4];
    const float* lq2b = (const float*)d_in[5];
    const float* lkvg = (const float*)d_in[6];
    const float* lkvb = (const float*)d_in[7];
    const float* wq1  = (const float*)d_in[8];
    const float* wq2  = (const float*)d_in[9];
    const float* cdw  = (const float*)d_in[10];
    const float* wf   = (const float*)d_in[11];
    float* out = (float*)d_out;

    char* ws = (char*)d_ws;
    size_t off = 0;
    auto carve = [&](size_t bytes) { char* p = ws + off; off += (bytes + 255) & ~(size_t)255; return p; };
    unsigned short* kvn  = (unsigned short*)carve((size_t)B_ * NTQ_ * TXT_ * 2);       // 67.1 MB
    unsigned short* kvt  = (unsigned short*)carve((size_t)B_ * TXT_ * NTP_ * 2);       // 67.1 MB
    unsigned short* wqt  = (unsigned short*)carve((size_t)2 * 512 * 1024 * 2);         // 2 MB
    unsigned short* wfb  = (unsigned short*)carve((size_t)1024 * 512 * 2);             // 1 MB
    float* qbias = (float*)carve((size_t)2 * 512 * 4);
    float* stats = (float*)carve((size_t)4 * BT_ * 4);                                 // denom[2BT] | avgs[BT] | maxe[BT]
    float* denom = stats;
    float* avgs  = stats + 2 * BT_;
    unsigned* maxe = (unsigned*)(stats + 3 * BT_);
    unsigned short* xn   = (unsigned short*)carve((size_t)BT_ * DIM_ * 2);             // 75.5 MB
    unsigned short* qbuf = (unsigned short*)carve((size_t)2 * BT_ * TXT_ * 2);         // 75.5 MB
    unsigned short* ob   = (unsigned short*)carve((size_t)2 * BT_ * TXT_ * 2);         // 75.5 MB
    unsigned short* Pm   = xn;     // P (36864x1024 bf16, per branch): xn dead after k_qgemm
    unsigned short* xse  = qbuf;   // safe: qbuf dead after last k_score

    // row 0 of output = x_cls
    hipMemcpyAsync(out, x, (size_t)B_ * DIM_ * sizeof(float), hipMemcpyDeviceToDevice, stream);

    k_prep<<<784, 256, 0, stream>>>(wq1, wq2, lq1g, lq2g, lq1b, lq2b, wf, wqt, qbias, wfb);
    k_lnorm<<<12800, 512, 0, stream>>>(tf, lkvg, lkvb, x, kvn, xn);
    k_kvt<<<8192, 256, 0, stream>>>(kvn, kvt);
    k_qgemm<<<2304, 256, 0, stream>>>(xn, wqt, qbias, qbuf);
    hipMemsetAsync(stats, 0, (size_t)4 * BT_ * 4, stream);
    // branch 0
    k_score<<<3072, 256, 0, stream>>>(qbuf, kvn, Pm, denom, 0);
    k_pv<<<1536, 256, 0, stream>>>(Pm, kvt, denom, ob, avgs, maxe, 0);
    // branch 1 (P buffer reused; stream-ordered)
    k_score<<<3072, 256, 0, stream>>>(qbuf, kvn, Pm, denom, 1);
    k_pv<<<1536, 256, 0, stream>>>(Pm, kvt, denom, ob, avgs, maxe, 1);
    k_xse<<<9216, 256, 0, stream>>>(ob, ob + (size_t)BT_ * TXT_, avgs, maxe, cdw, xse);
    k_fgemm<<<2304, 256, 0, stream>>>(xse, wfb, out);
}

// Round 8
// 612.566 us; speedup vs baseline: 1.2933x; 1.0194x over previous
//
#include <hip/hip_runtime.h>

// ---------------- problem constants ----------------
#define B_    64
#define TOK_  576
#define DIM_  1024
#define TXT_  512
#define NT_   1000
#define NTQ_  1024                 // kvn padded rows (zero-filled 1000..1023)
#define NTP_  1024                 // kvt padded cols / P padded cols
#define H_    24
#define BT_   (B_ * TOK_)          // 36864 rows
static constexpr float SCALE_ = 0.0441941738241592f;   // 512^-0.5

typedef __bf16 bf16x8 __attribute__((ext_vector_type(8)));
typedef float  f32x4  __attribute__((ext_vector_type(4)));

__device__ __forceinline__ unsigned short f2bf(float f) {
    unsigned u = __float_as_uint(f);
    u += 0x7fffu + ((u >> 16) & 1u);
    return (unsigned short)(u >> 16);
}
__device__ __forceinline__ float bf2f(unsigned short h) {
    return __uint_as_float(((unsigned)h) << 16);
}
__device__ __forceinline__ f32x4 mfma16(bf16x8 a, bf16x8 b, f32x4 c) {
    return __builtin_amdgcn_mfma_f32_16x16x32_bf16(a, b, c, 0, 0, 0);
}
__device__ __forceinline__ void unpack8(uint4 v, float* f) {
    unsigned a0 = v.x, a1 = v.y, a2 = v.z, a3 = v.w;
    f[0] = bf2f((unsigned short)(a0 & 0xffff)); f[1] = bf2f((unsigned short)(a0 >> 16));
    f[2] = bf2f((unsigned short)(a1 & 0xffff)); f[3] = bf2f((unsigned short)(a1 >> 16));
    f[4] = bf2f((unsigned short)(a2 & 0xffff)); f[5] = bf2f((unsigned short)(a2 >> 16));
    f[6] = bf2f((unsigned short)(a3 & 0xffff)); f[7] = bf2f((unsigned short)(a3 >> 16));
}
// order-preserving float->uint encoding for atomicMax over signed floats
__device__ __forceinline__ unsigned encmax(float f) {
    unsigned u = __float_as_uint(f);
    return (u & 0x80000000u) ? ~u : (u | 0x80000000u);
}
__device__ __forceinline__ float decmax(unsigned k) {
    unsigned u = (k & 0x80000000u) ? (k ^ 0x80000000u) : ~k;
    return __uint_as_float(u);
}

// async global->LDS, 16B per lane; lds base wave-uniform, lanes land at base + lane*16
typedef const __attribute__((address_space(1))) unsigned int* as1_u32p;
typedef __attribute__((address_space(3))) unsigned int* as3_u32p;
__device__ __forceinline__ void gll16(const void* g, void* l) {
    __builtin_amdgcn_global_load_lds((as1_u32p)g, (as3_u32p)l, 16, 0, 0);
}

// ---------------- merged prep: [0,256) wq | [256,272) qbias | [272,784) f2bf | [784,928) stats zero ----------------
__global__ void k_prep(const float* __restrict__ wq1, const float* __restrict__ wq2,
                       const float* __restrict__ g1, const float* __restrict__ g2,
                       const float* __restrict__ b1, const float* __restrict__ b2,
                       const float* __restrict__ wf,
                       unsigned short* __restrict__ wqt, float* __restrict__ qbias,
                       unsigned short* __restrict__ wfb, float* __restrict__ stats) {
    __shared__ float tile[64][68];
    int bx = blockIdx.x, t = threadIdx.x;
    if (bx < 256) {
        // Wq (1024x512 f32), rows pre-scaled by LN gamma -> WqT bf16 [branch][512][1024]
        int br = bx >> 7, kt = (bx >> 3) & 15, nt = bx & 7;
        const float* wq = br ? wq2 : wq1;
        const float* gg = br ? g2 : g1;
#pragma unroll
        for (int i = 0; i < 4; ++i) {
            int idx4 = t + i * 256;
            int kl = idx4 >> 4, n4 = (idx4 & 15) * 4;
            float gv = gg[kt * 64 + kl];
            float4 v = *reinterpret_cast<const float4*>(wq + (size_t)(kt * 64 + kl) * 512 + nt * 64 + n4);
            tile[kl][n4 + 0] = v.x * gv; tile[kl][n4 + 1] = v.y * gv;
            tile[kl][n4 + 2] = v.z * gv; tile[kl][n4 + 3] = v.w * gv;
        }
        __syncthreads();
#pragma unroll
        for (int i = 0; i < 4; ++i) {
            int idx4 = t + i * 256;
            int nl = idx4 >> 4, k4 = (idx4 & 15) * 4;
            ushort4 o = make_ushort4(f2bf(tile[k4 + 0][nl]), f2bf(tile[k4 + 1][nl]),
                                     f2bf(tile[k4 + 2][nl]), f2bf(tile[k4 + 3][nl]));
            *reinterpret_cast<ushort4*>(wqt + (size_t)br * 512 * 1024 + (size_t)(nt * 64 + nl) * 1024 + kt * 64 + k4) = o;
        }
    } else if (bx < 272) {
        // qbias[br][e] = sum_d beta[d] * Wq[d][e]
        int bb2 = bx - 256;
        int br = bb2 >> 3, e0 = (bb2 & 7) * 64;
        int e = e0 + (t & 63), part = t >> 6;
        const float* wq = br ? wq2 : wq1;
        const float* bb = br ? b2 : b1;
        float s = 0.f;
        for (int d = part * 256; d < part * 256 + 256; ++d) s += bb[d] * wq[(size_t)d * 512 + e];
        float* red = &tile[0][0];
        red[t] = s;
        __syncthreads();
        if (t < 64) qbias[br * 512 + e0 + t] = red[t] + red[64 + t] + red[128 + t] + red[192 + t];
    } else if (bx < 784) {
        // Wf f32 -> bf16 (131072 float4 groups over 512 blocks)
        int i = (bx - 272) * 256 + t;
        float4 v = *reinterpret_cast<const float4*>(wf + (size_t)i * 4);
        ushort4 o = make_ushort4(f2bf(v.x), f2bf(v.y), f2bf(v.z), f2bf(v.w));
        *reinterpret_cast<ushort4*>(wfb + (size_t)i * 4) = o;
    } else {
        // zero stats (denom[2BT] | avgs[BT] | maxe[BT]) = 4*BT floats = 36864 float4
        int i = (bx - 784) * 256 + t;
        *reinterpret_cast<float4*>(stats + (size_t)i * 4) = make_float4(0.f, 0.f, 0.f, 0.f);
    }
}

// ---------------- merged layernorms, wave-per-row, SOURCE-ORDER mapping (sequential reads) ----------------
// [0,8192): tf rows (trow = n*64+b tf-storage order) -> kvn bf16 [b][n_pad1024][e]
// [8192,12800): x rows (g = (tk+1)*64+b x-storage order) -> xn (normalized only)
__global__ __launch_bounds__(512, 2) void k_lnorm(const float* __restrict__ tf,
                                                  const float* __restrict__ g,
                                                  const float* __restrict__ bta,
                                                  const float* __restrict__ x,
                                                  unsigned short* __restrict__ kvn,
                                                  unsigned short* __restrict__ xn) {
    int bid = blockIdx.x;
    int l = threadIdx.x & 63;
    if (bid < 8192) {
        int trow = bid * 8 + (threadIdx.x >> 6);     // tf-order: n*64 + b  (covers n in [0,1024))
        int n = trow >> 6, b = trow & 63;
        unsigned short* dst = kvn + ((size_t)b * NTQ_ + n) * TXT_ + l * 8;
        if (n >= NT_) {                              // zero-pad rows (no tf data)
            *reinterpret_cast<uint4*>(dst) = make_uint4(0, 0, 0, 0);
            return;
        }
        const float* src = tf + (size_t)trow * TXT_ + l * 8;   // fully sequential across grid
        float4 v0 = *reinterpret_cast<const float4*>(src);
        float4 v1 = *reinterpret_cast<const float4*>(src + 4);
        float s  = v0.x + v0.y + v0.z + v0.w + v1.x + v1.y + v1.z + v1.w;
        float ss = v0.x * v0.x + v0.y * v0.y + v0.z * v0.z + v0.w * v0.w
                 + v1.x * v1.x + v1.y * v1.y + v1.z * v1.z + v1.w * v1.w;
#pragma unroll
        for (int d = 1; d < 64; d <<= 1) { s += __shfl_xor(s, d); ss += __shfl_xor(ss, d); }
        float m = s * (1.f / TXT_);
        float rs = rsqrtf(ss * (1.f / TXT_) - m * m + 1e-5f);
        float4 g0 = *reinterpret_cast<const float4*>(g + l * 8);
        float4 g1 = *reinterpret_cast<const float4*>(g + l * 8 + 4);
        float4 b0 = *reinterpret_cast<const float4*>(bta + l * 8);
        float4 b1 = *reinterpret_cast<const float4*>(bta + l * 8 + 4);
        unsigned r0 = (unsigned)f2bf((v0.x - m) * rs * g0.x + b0.x) | ((unsigned)f2bf((v0.y - m) * rs * g0.y + b0.y) << 16);
        unsigned r1 = (unsigned)f2bf((v0.z - m) * rs * g0.z + b0.z) | ((unsigned)f2bf((v0.w - m) * rs * g0.w + b0.w) << 16);
        unsigned r2 = (unsigned)f2bf((v1.x - m) * rs * g1.x + b1.x) | ((unsigned)f2bf((v1.y - m) * rs * g1.y + b1.y) << 16);
        unsigned r3 = (unsigned)f2bf((v1.z - m) * rs * g1.z + b1.z) | ((unsigned)f2bf((v1.w - m) * rs * g1.w + b1.w) << 16);
        *reinterpret_cast<uint4*>(dst) = make_uint4(r0, r1, r2, r3);
    } else {
        int gr = 64 + (bid - 8192) * 8 + (threadIdx.x >> 6);  // x row index in [64, 36928), x-storage order
        int b = gr & 63, tk = (gr >> 6) - 1;
        const float* src = x + (size_t)gr * DIM_ + l * 16;    // fully sequential across grid
        float4 v[4];
#pragma unroll
        for (int j = 0; j < 4; ++j) v[j] = *reinterpret_cast<const float4*>(src + j * 4);
        float s = 0.f, ss = 0.f;
#pragma unroll
        for (int j = 0; j < 4; ++j) {
            s += v[j].x + v[j].y + v[j].z + v[j].w;
            ss += v[j].x * v[j].x + v[j].y * v[j].y + v[j].z * v[j].z + v[j].w * v[j].w;
        }
#pragma unroll
        for (int d = 1; d < 64; d <<= 1) { s += __shfl_xor(s, d); ss += __shfl_xor(ss, d); }
        float m = s * (1.f / DIM_);
        float rs = rsqrtf(ss * (1.f / DIM_) - m * m + 1e-5f);
        unsigned short* dst = xn + ((size_t)b * TOK_ + tk) * DIM_ + l * 16;
#pragma unroll
        for (int h = 0; h < 2; ++h) {
            unsigned r0 = (unsigned)f2bf((v[2*h].x - m) * rs) | ((unsigned)f2bf((v[2*h].y - m) * rs) << 16);
            unsigned r1 = (unsigned)f2bf((v[2*h].z - m) * rs) | ((unsigned)f2bf((v[2*h].w - m) * rs) << 16);
            unsigned r2 = (unsigned)f2bf((v[2*h+1].x - m) * rs) | ((unsigned)f2bf((v[2*h+1].y - m) * rs) << 16);
            unsigned r3 = (unsigned)f2bf((v[2*h+1].z - m) * rs) | ((unsigned)f2bf((v[2*h+1].w - m) * rs) << 16);
            *reinterpret_cast<uint4*>(dst + h * 8) = make_uint4(r0, r1, r2, r3);
        }
    }
}

// ---------------- kv transpose:  kvn [b][n][e] -> kvt [b][e][n_pad1024] ----------------
__global__ void k_kvt(const unsigned short* __restrict__ kvn, unsigned short* __restrict__ kvt) {
    __shared__ unsigned short tile[64][68];
    int bx = blockIdx.x;
    int b = bx >> 7, rem = bx & 127, et = rem >> 4, nt = rem & 15;
    int t = threadIdx.x;
#pragma unroll
    for (int i = 0; i < 4; ++i) {
        int idx4 = t + i * 256;
        int nl = idx4 >> 4, e4 = (idx4 & 15) * 4;
        int ng = nt * 64 + nl;
        ushort4 v = make_ushort4(0, 0, 0, 0);
        if (ng < NT_) v = *reinterpret_cast<const ushort4*>(kvn + ((size_t)b * NTQ_ + ng) * TXT_ + et * 64 + e4);
        tile[nl][e4 + 0] = v.x; tile[nl][e4 + 1] = v.y; tile[nl][e4 + 2] = v.z; tile[nl][e4 + 3] = v.w;
    }
    __syncthreads();
#pragma unroll
    for (int i = 0; i < 4; ++i) {
        int idx4 = t + i * 256;
        int el = idx4 >> 4, n4 = (idx4 & 15) * 4;
        ushort4 o = make_ushort4(tile[n4 + 0][el], tile[n4 + 1][el], tile[n4 + 2][el], tile[n4 + 3][el]);
        *reinterpret_cast<ushort4*>(kvt + ((size_t)b * TXT_ + et * 64 + el) * NTP_ + nt * 64 + n4) = o;
    }
}

// ---------------- 128x128xK bf16 GEMM mainloop, global_load_lds staging (m97 structure) ----------------
// A:[M][K], B:[N][K], both k-contiguous.
__device__ __forceinline__ void gemm_loop_gll(const unsigned short* __restrict__ A,
                                              const unsigned short* __restrict__ Bp,
                                              int K, unsigned short* a_lds, unsigned short* b_lds,
                                              int tid, f32x4 acc[4][4]) {
    const int l = tid & 63, w = tid >> 6;
    const int l16 = l & 15, lg = l >> 4;
    const int wm = w & 1, wn = w >> 1;
    const f32x4 fz = {0.f, 0.f, 0.f, 0.f};
#pragma unroll
    for (int mt = 0; mt < 4; ++mt)
#pragma unroll
        for (int nt = 0; nt < 4; ++nt) acc[mt][nt] = fz;
    const int lrow = l >> 3;               // 0..7
    const int k8g = (l & 7) ^ lrow;        // pre-swizzled source granule
    const int nk = K >> 6;
    for (int kt = 0; kt < nk; ++kt) {
#pragma unroll
        for (int i = 0; i < 4; ++i) {
            int row = i * 32 + w * 8 + lrow;
            gll16(A + (size_t)row * K + kt * 64 + k8g * 8, &a_lds[(i * 256 + w * 64) * 8]);
        }
#pragma unroll
        for (int i = 0; i < 4; ++i) {
            int row = i * 32 + w * 8 + lrow;
            gll16(Bp + (size_t)row * K + kt * 64 + k8g * 8, &b_lds[(i * 256 + w * 64) * 8]);
        }
        __syncthreads();
#pragma unroll
        for (int kk = 0; kk < 2; ++kk) {
            bf16x8 af[4], bff[4];
#pragma unroll
            for (int mt = 0; mt < 4; ++mt) {
                int row = wm * 64 + mt * 16 + l16;
                int gs = (kk * 4 + lg) ^ (row & 7);
                af[mt] = *reinterpret_cast<const bf16x8*>(a_lds + row * 64 + gs * 8);
            }
#pragma unroll
            for (int nt = 0; nt < 4; ++nt) {
                int row = wn * 64 + nt * 16 + l16;
                int gs = (kk * 4 + lg) ^ (row & 7);
                bff[nt] = *reinterpret_cast<const bf16x8*>(b_lds + row * 64 + gs * 8);
            }
#pragma unroll
            for (int mt = 0; mt < 4; ++mt)
#pragma unroll
                for (int nt = 0; nt < 4; ++nt)
                    acc[mt][nt] = mfma16(af[mt], bff[nt], acc[mt][nt]);
        }
        __syncthreads();
    }
}

// ---------------- 96x128xK variant (M-tile 96 keeps tiles inside one b: 576 = 6*96) ----------------
__device__ __forceinline__ void gemm_loop96(const unsigned short* __restrict__ A,
                                            const unsigned short* __restrict__ Bp,
                                            int K, unsigned short* a_lds, unsigned short* b_lds,
                                            int tid, f32x4 acc[3][4]) {
    const int l = tid & 63, w = tid >> 6;
    const int l16 = l & 15, lg = l >> 4;
    const int wm = w & 1, wn = w >> 1;
    const f32x4 fz = {0.f, 0.f, 0.f, 0.f};
#pragma unroll
    for (int mt = 0; mt < 3; ++mt)
#pragma unroll
        for (int nt = 0; nt < 4; ++nt) acc[mt][nt] = fz;
    const int lrow = l >> 3;
    const int k8g = (l & 7) ^ lrow;
    const int nk = K >> 6;
    for (int kt = 0; kt < nk; ++kt) {
#pragma unroll
        for (int i = 0; i < 3; ++i) {
            int row = i * 32 + w * 8 + lrow;
            gll16(A + (size_t)row * K + kt * 64 + k8g * 8, &a_lds[(i * 256 + w * 64) * 8]);
        }
#pragma unroll
        for (int i = 0; i < 4; ++i) {
            int row = i * 32 + w * 8 + lrow;
            gll16(Bp + (size_t)row * K + kt * 64 + k8g * 8, &b_lds[(i * 256 + w * 64) * 8]);
        }
        __syncthreads();
#pragma unroll
        for (int kk = 0; kk < 2; ++kk) {
            bf16x8 af[3], bff[4];
#pragma unroll
            for (int mt = 0; mt < 3; ++mt) {
                int row = wm * 48 + mt * 16 + l16;
                int gs = (kk * 4 + lg) ^ (row & 7);
                af[mt] = *reinterpret_cast<const bf16x8*>(a_lds + row * 64 + gs * 8);
            }
#pragma unroll
            for (int nt = 0; nt < 4; ++nt) {
                int row = wn * 64 + nt * 16 + l16;
                int gs = (kk * 4 + lg) ^ (row & 7);
                bff[nt] = *reinterpret_cast<const bf16x8*>(b_lds + row * 64 + gs * 8);
            }
#pragma unroll
            for (int mt = 0; mt < 3; ++mt)
#pragma unroll
                for (int nt = 0; nt < 4; ++nt)
                    acc[mt][nt] = mfma16(af[mt], bff[nt], acc[mt][nt]);
        }
        __syncthreads();
    }
}

// q GEMM:  q[br] = (xn @ (diag(g)Wq[br])^T + bias) * SCALE  -> bf16 (36864x512)
__global__ __launch_bounds__(256, 4) void k_qgemm(const unsigned short* __restrict__ xn,
                                                  const unsigned short* __restrict__ wqt,
                                                  const float* __restrict__ qbias,
                                                  unsigned short* __restrict__ qb) {
    int bid = blockIdx.x;                        // 2304 = 4bn x 288bm x 2br
    int vb = (bid & 7) * 288 + (bid >> 3);       // XCD-contiguous
    int bn = vb & 3;
    int t = vb >> 2;
    int br = (t >= 288) ? 1 : 0;
    int bm = t - br * 288;
    const unsigned short* A = xn + (size_t)bm * 128 * DIM_;
    const unsigned short* Bp = wqt + (size_t)br * 512 * 1024 + (size_t)bn * 128 * 1024;
    unsigned short* C = qb + (size_t)br * BT_ * TXT_;
    const float* bias = qbias + br * 512;
    __shared__ unsigned short a_lds[128 * 64];
    __shared__ unsigned short b_lds[128 * 64];
    f32x4 acc[4][4];
    gemm_loop_gll(A, Bp, DIM_, a_lds, b_lds, threadIdx.x, acc);
    const int l = threadIdx.x & 63, w = threadIdx.x >> 6;
    const int l16 = l & 15, lg = l >> 4, wm = w & 1, wn = w >> 1;
#pragma unroll
    for (int mt = 0; mt < 4; ++mt)
#pragma unroll
        for (int nt = 0; nt < 4; ++nt) {
            int col = bn * 128 + wn * 64 + nt * 16 + l16;
            float bv = bias[col];
#pragma unroll
            for (int r = 0; r < 4; ++r) {
                int row = bm * 128 + wm * 64 + mt * 16 + lg * 4 + r;
                C[(size_t)row * TXT_ + col] = f2bf((acc[mt][nt][r] + bv) * SCALE_);
            }
        }
}

// score GEMM: P = exp(q @ kvn^T) per branch, + row-sum atomics into denom
__global__ __launch_bounds__(256, 4) void k_score(const unsigned short* __restrict__ qbuf,
                                                  const unsigned short* __restrict__ kvn,
                                                  unsigned short* __restrict__ P,
                                                  float* __restrict__ denom, int br) {
    int bid = blockIdx.x;                        // 3072 = 64b x 6mt x 8nt
    int vb = (bid & 7) * 384 + (bid >> 3);       // XCD-contiguous, 8 b's per XCD
    int tile = vb % 48, b = vb / 48;
    int mt = tile >> 3, nt = tile & 7;
    const unsigned short* A = qbuf + ((size_t)br * BT_ + (size_t)b * TOK_ + mt * 96) * TXT_;
    const unsigned short* Bp = kvn + (size_t)b * NTQ_ * TXT_ + (size_t)nt * 128 * TXT_;
    __shared__ unsigned short a_lds[96 * 64];
    __shared__ unsigned short b_lds[128 * 64];
    f32x4 acc[3][4];
    gemm_loop96(A, Bp, TXT_, a_lds, b_lds, threadIdx.x, acc);
    const int l = threadIdx.x & 63, w = threadIdx.x >> 6;
    const int l16 = l & 15, lg = l >> 4, wm = w & 1, wn = w >> 1;
    float* dn = denom + (size_t)br * BT_;
#pragma unroll
    for (int mt2 = 0; mt2 < 3; ++mt2)
#pragma unroll
        for (int r = 0; r < 4; ++r) {
            int row = b * TOK_ + mt * 96 + wm * 48 + mt2 * 16 + lg * 4 + r;
            float s = 0.f;
#pragma unroll
            for (int nt2 = 0; nt2 < 4; ++nt2) {
                int col = nt * 128 + wn * 64 + nt2 * 16 + l16;
                float p = (col < NT_) ? __expf(acc[mt2][nt2][r]) : 0.f;
                s += p;
                P[(size_t)row * NTP_ + col] = f2bf(p);
            }
#pragma unroll
            for (int d = 1; d < 16; d <<= 1) s += __shfl_xor(s, d);
            if (l16 == 0) atomicAdd(&dn[row], s);
        }
}

// PV GEMM: O = (P @ kvt^T) / denom -> bf16; fused per-row sum (br0) / max (br1) atomics
__global__ __launch_bounds__(256, 4) void k_pv(const unsigned short* __restrict__ P,
                                               const unsigned short* __restrict__ kvt,
                                               const float* __restrict__ denom,
                                               unsigned short* __restrict__ ob,
                                               float* __restrict__ avgs,
                                               unsigned* __restrict__ maxe, int br) {
    int bid = blockIdx.x;                        // 1536 = 64b x 6mt x 4nt
    int vb = (bid & 7) * 192 + (bid >> 3);       // XCD-contiguous, 8 b's per XCD
    int tile = vb % 24, b = vb / 24;
    int mt = tile >> 2, nt = tile & 3;
    const unsigned short* A = P + ((size_t)b * TOK_ + mt * 96) * NTP_;
    const unsigned short* Bp = kvt + (size_t)b * TXT_ * NTP_ + (size_t)nt * 128 * NTP_;
    __shared__ unsigned short a_lds[96 * 64];
    __shared__ unsigned short b_lds[128 * 64];
    f32x4 acc[3][4];
    gemm_loop96(A, Bp, NTP_, a_lds, b_lds, threadIdx.x, acc);
    const int l = threadIdx.x & 63, w = threadIdx.x >> 6;
    const int l16 = l & 15, lg = l >> 4, wm = w & 1, wn = w >> 1;
    const float* dn = denom + (size_t)br * BT_;
#pragma unroll
    for (int mt2 = 0; mt2 < 3; ++mt2)
#pragma unroll
        for (int r = 0; r < 4; ++r) {
            int row = b * TOK_ + mt * 96 + wm * 48 + mt2 * 16 + lg * 4 + r;
            float inv = 1.f / dn[row];
            unsigned short* dst = ob + ((size_t)br * BT_ + row) * TXT_;
            float sum = 0.f, mx = -1e30f;
#pragma unroll
            for (int nt2 = 0; nt2 < 4; ++nt2) {
                int col = nt * 128 + wn * 64 + nt2 * 16 + l16;
                float o = acc[mt2][nt2][r] * inv;
                dst[col] = f2bf(o);
                sum += o;
                mx = fmaxf(mx, o);
            }
#pragma unroll
            for (int d = 1; d < 16; d <<= 1) {
                sum += __shfl_xor(sum, d);
                mx = fmaxf(mx, __shfl_xor(mx, d));
            }
            if (l16 == 0) {
                if (br == 0) atomicAdd(&avgs[row], sum);
                else         atomicMax(&maxe[row], encmax(mx));
            }
        }
}

// final GEMM: y = xse (36864x512) @ Wf^T (1024x512) -> fp32 scattered into out layout
__global__ __launch_bounds__(256, 4) void k_fgemm(const unsigned short* __restrict__ xse,
                                                  const unsigned short* __restrict__ wfb,
                                                  float* __restrict__ out) {
    int bid = blockIdx.x;                        // 2304 = 8bn x 288bm
    int vb = (bid & 7) * 288 + (bid >> 3);
    int bn = vb & 7, bm = vb >> 3;
    const unsigned short* A = xse + (size_t)bm * 128 * TXT_;
    const unsigned short* Bp = wfb + (size_t)bn * 128 * TXT_;
    __shared__ unsigned short a_lds[128 * 64];
    __shared__ unsigned short b_lds[128 * 64];
    f32x4 acc[4][4];
    gemm_loop_gll(A, Bp, TXT_, a_lds, b_lds, threadIdx.x, acc);
    const int l = threadIdx.x & 63, w = threadIdx.x >> 6;
    const int l16 = l & 15, lg = l >> 4, wm = w & 1, wn = w >> 1;
#pragma unroll
    for (int mt = 0; mt < 4; ++mt)
#pragma unroll
        for (int r = 0; r < 4; ++r) {
            int rowg = bm * 128 + wm * 64 + mt * 16 + lg * 4 + r;
            int b = rowg / TOK_, tk = rowg - b * TOK_;
            float* dst = out + ((size_t)(tk + 1) * B_ + b) * DIM_;
#pragma unroll
            for (int nt = 0; nt < 4; ++nt) {
                int col = bn * 128 + wn * 64 + nt * 16 + l16;
                dst[col] = acc[mt][nt][r];
            }
        }
}

// ---------------- x_se = o1*g1 + o2*g2 -> bf16, with gate conv fused (lane 0 per row) ----------------
__global__ void k_xse(const unsigned short* __restrict__ o1, const unsigned short* __restrict__ o2,
                      const float* __restrict__ avgs, const unsigned* __restrict__ maxe,
                      const float* __restrict__ cdw, unsigned short* __restrict__ xse) {
    int idx8 = blockIdx.x * 256 + threadIdx.x;    // < 36864*64
    int bt = idx8 >> 6, e8 = threadIdx.x & 63;
    float gg1 = 0.f, gg2 = 0.f;
    if (e8 == 0) {
        int b = bt / TOK_, hw = bt - b * TOK_, h = hw / H_, ww = hw - h * H_;
        float a1 = 0.f, a2 = 0.f;
#pragma unroll
        for (int ky = 0; ky < 3; ++ky)
#pragma unroll
            for (int kx = 0; kx < 3; ++kx) {
                int hh = h + ky - 1, wx = ww + kx - 1;
                if (hh >= 0 && hh < H_ && wx >= 0 && wx < H_) {
                    float wv = cdw[ky * 3 + kx];
                    int s = b * TOK_ + hh * H_ + wx;
                    a1 += wv * avgs[s] * (1.f / TXT_);
                    a2 += wv * decmax(maxe[s]);
                }
            }
        gg1 = 1.f / (1.f + __expf(-a1));
        gg2 = 1.f / (1.f + __expf(-a2));
    }
    gg1 = __shfl(gg1, 0);
    gg2 = __shfl(gg2, 0);
    float f1[8], f2[8];
    unpack8(*reinterpret_cast<const uint4*>(o1 + (size_t)bt * TXT_ + e8 * 8), f1);
    unpack8(*reinterpret_cast<const uint4*>(o2 + (size_t)bt * TXT_ + e8 * 8), f2);
    unsigned r[4];
#pragma unroll
    for (int j = 0; j < 4; ++j) {
        unsigned lo = f2bf(f1[2 * j] * gg1 + f2[2 * j] * gg2);
        unsigned hi = f2bf(f1[2 * j + 1] * gg1 + f2[2 * j + 1] * gg2);
        r[j] = lo | (hi << 16);
    }
    uint4 o = make_uint4(r[0], r[1], r[2], r[3]);
    *reinterpret_cast<uint4*>(xse + (size_t)bt * TXT_ + e8 * 8) = o;
}

// ---------------- launcher ----------------
extern "C" void kernel_launch(void* const* d_in, const int* in_sizes, int n_in,
                              void* d_out, int out_size, void* d_ws, size_t ws_size,
                              hipStream_t stream) {
    (void)in_sizes; (void)n_in; (void)out_size; (void)ws_size;
    const float* x    = (const float*)d_in[0];
    const float* tf   = (const float*)d_in[1];
    const float* lq1g = (const float*)d_in[2];
    const float* lq1b = (const float*)d_in[3];
    const float* lq2g = (const float*)d_in[4];
    const float* lq2b = (const float*)d_in[5];
    const float* lkvg = (const float*)d_in[6];
    const float* lkvb = (const float*)d_in[7];
    const float* wq1  = (const float*)d_in[8];
    const float* wq2  = (const float*)d_in[9];
    const float* cdw  = (const float*)d_in[10];
    const float* wf   = (const float*)d_in[11];
    float* out = (float*)d_out;

    char* ws = (char*)d_ws;
    size_t off = 0;
    auto carve = [&](size_t bytes) { char* p = ws + off; off += (bytes + 255) & ~(size_t)255; return p; };
    unsigned short* kvn  = (unsigned short*)carve((size_t)B_ * NTQ_ * TXT_ * 2);       // 67.1 MB
    unsigned short* kvt  = (unsigned short*)carve((size_t)B_ * TXT_ * NTP_ * 2);       // 67.1 MB
    unsigned short* wqt  = (unsigned short*)carve((size_t)2 * 512 * 1024 * 2);         // 2 MB
    unsigned short* wfb  = (unsigned short*)carve((size_t)1024 * 512 * 2);             // 1 MB
    float* qbias = (float*)carve((size_t)2 * 512 * 4);
    float* stats = (float*)carve((size_t)4 * BT_ * 4);                                 // denom[2BT] | avgs[BT] | maxe[BT]
    float* denom = stats;
    float* avgs  = stats + 2 * BT_;
    unsigned* maxe = (unsigned*)(stats + 3 * BT_);
    unsigned short* xn   = (unsigned short*)carve((size_t)BT_ * DIM_ * 2);             // 75.5 MB
    unsigned short* qbuf = (unsigned short*)carve((size_t)2 * BT_ * TXT_ * 2);         // 75.5 MB
    unsigned short* ob   = (unsigned short*)carve((size_t)2 * BT_ * TXT_ * 2);         // 75.5 MB
    unsigned short* Pm   = xn;     // P (36864x1024 bf16, per branch): xn dead after k_qgemm
    unsigned short* xse  = qbuf;   // safe: qbuf dead after last k_score

    // row 0 of output = x_cls
    hipMemcpyAsync(out, x, (size_t)B_ * DIM_ * sizeof(float), hipMemcpyDeviceToDevice, stream);

    k_prep<<<928, 256, 0, stream>>>(wq1, wq2, lq1g, lq2g, lq1b, lq2b, wf, wqt, qbias, wfb, stats);
    k_lnorm<<<12800, 512, 0, stream>>>(tf, lkvg, lkvb, x, kvn, xn);
    k_kvt<<<8192, 256, 0, stream>>>(kvn, kvt);
    k_qgemm<<<2304, 256, 0, stream>>>(xn, wqt, qbias, qbuf);
    // branch 0
    k_score<<<3072, 256, 0, stream>>>(qbuf, kvn, Pm, denom, 0);
    k_pv<<<1536, 256, 0, stream>>>(Pm, kvt, denom, ob, avgs, maxe, 0);
    // branch 1 (P buffer reused; stream-ordered)
    k_score<<<3072, 256, 0, stream>>>(qbuf, kvn, Pm, denom, 1);
    k_pv<<<1536, 256, 0, stream>>>(Pm, kvt, denom, ob, avgs, maxe, 1);
    k_xse<<<9216, 256, 0, stream>>>(ob, ob + (size_t)BT_ * TXT_, avgs, maxe, cdw, xse);
    k_fgemm<<<2304, 256, 0, stream>>>(xse, wfb, out);
}